// Round 18
// baseline (201.431 us; speedup 1.0000x reference)
//
#include <hip/hip_runtime.h>
#include <hip/hip_bf16.h>
#include <cstddef>

// Problem constants (N, D, S, H, QP, VP) = (512, 256, 32, 4, 8, 8)
#define N_NODES 512
#define DIM     256
#define H_HEADS 4
#define PAIR_CN 56    // S + 3*VP
#define P3_N    96    // H*QP*3
#define FD_N    112   // P3 + 16
#define HPC     224   // H * PAIR_C

typedef _Float16 h2v  __attribute__((ext_vector_type(2)));
typedef _Float16 f16x8 __attribute__((ext_vector_type(8)));
typedef float    f32x4 __attribute__((ext_vector_type(4)));

__device__ __forceinline__ bool mask_true(const void* m, int idx) {
    if (((const unsigned char*)m)[idx] != 0) return true;
    return ((const int*)m)[idx] != 0;
}
__device__ __forceinline__ unsigned packh2(float a, float b) {
    _Float16 ha = (_Float16)a, hb = (_Float16)b;
    unsigned short ua, ub;
    __builtin_memcpy(&ua, &ha, 2); __builtin_memcpy(&ub, &hb, 2);
    return (unsigned)ua | ((unsigned)ub << 16);
}
__device__ __forceinline__ float h2lof(unsigned u) {
    unsigned short t = (unsigned short)(u & 0xffff);
    _Float16 h; __builtin_memcpy(&h, &t, 2); return (float)h;
}
__device__ __forceinline__ float h2hif(unsigned u) {
    unsigned short t = (unsigned short)(u >> 16);
    _Float16 h; __builtin_memcpy(&h, &t, 2); return (float)h;
}
__device__ __forceinline__ float dot2u(unsigned a, unsigned b, float c) {
#if __has_builtin(__builtin_amdgcn_fdot2)
    h2v ha, hb;
    __builtin_memcpy(&ha, &a, 4);
    __builtin_memcpy(&hb, &b, 4);
    return __builtin_amdgcn_fdot2(ha, hb, c, false);
#else
    return c + h2lof(a)*h2lof(b) + h2hif(a)*h2hif(b);
#endif
}
__device__ __forceinline__ f32x4 mfma16(uint4 a, uint4 b, f32x4 c) {
    f16x8 af, bf;
    __builtin_memcpy(&af, &a, 16);
    __builtin_memcpy(&bf, &b, 16);
    return __builtin_amdgcn_mfma_f32_16x16x32_f16(af, bf, c, 0, 0, 0);
}

// ---------------------------------------------------------------------------
// Fused kernel: proj phase -> grid barrier -> attn phase.
// Grid 256 x 1024 (1 block/CU, all co-resident).
// ---------------------------------------------------------------------------
__global__ __launch_bounds__(1024) void fused_kernel(
    const float* __restrict__ local, const float* __restrict__ pos,
    const float* __restrict__ qls, const float* __restrict__ qlo,
    const float* __restrict__ kls, const float* __restrict__ klo,
    const float* __restrict__ w_q, const float* __restrict__ b_q,
    const float* __restrict__ w_k, const float* __restrict__ b_k,
    const float* __restrict__ w_v, const float* __restrict__ b_v,
    const float* __restrict__ w_qp, const float* __restrict__ b_qp,
    const float* __restrict__ w_kp, const float* __restrict__ b_kp,
    const float* __restrict__ w_vp, const float* __restrict__ b_vp,
    const float* __restrict__ w_bias, const float* __restrict__ b_bias,
    const float* __restrict__ gamma,
    const float* __restrict__ remb, const float* __restrict__ w_pair,
    const float* __restrict__ w_out,
    const int* __restrict__ resi, const int* __restrict__ chain,
    const int* __restrict__ batch, const void* __restrict__ maskp,
    unsigned* __restrict__ qnP, unsigned* __restrict__ knT4,
    unsigned* __restrict__ qpP, unsigned* __restrict__ kpT4,
    unsigned* __restrict__ BF,
    unsigned* __restrict__ woPk, unsigned* __restrict__ wp2,
    unsigned* __restrict__ remb2,
    float* __restrict__ jinfo, float* __restrict__ iinfo,
    unsigned* __restrict__ barCnt,
    float* __restrict__ out)
{
    const int ib  = blockIdx.x * 2;
    const int i0  = ib;
    const int tid = threadIdx.x;

    // ---- proj shared ----
    __shared__ float xL[2][DIM];
    __shared__ float qraw[2][128];
    __shared__ float kraw[2][128];
    __shared__ float stat[2][16];
    __shared__ float qpL[2][P3_N];
    __shared__ float kpbL[2][P3_N];
    __shared__ float wbS[384];
    // ---- attn shared ----
    __shared__ unsigned qpkL[2][64];
    __shared__ unsigned qspkL[2][48];
    __shared__ unsigned wbPk[H_HEADS][8];
    __shared__ __align__(16) unsigned rbfP[2][N_NODES][9];
    __shared__ __align__(16) unsigned attnH2[8][260];
    __shared__ float    mxW[16][4], smW[16][4];
    __shared__ float    asL2[2][H_HEADS];
    __shared__ float    qpiL2[2][P3_N];
    __shared__ float    GLfF2[2][H_HEADS][P3_N];
    __shared__ float    GLfR2[2][H_HEADS][16];
    __shared__ unsigned GLf22[2][H_HEADS][56];
    __shared__ unsigned abktP2[2][H_HEADS][33];
    __shared__ float    resL2[2][HPC];
    __shared__ unsigned resH2[2][FD_N];
    __shared__ float    abktW8[8][2][H_HEADS][66];

    // =====================================================================
    // PROJ PHASE
    // =====================================================================
    if (blockIdx.x < 16) {
        for (int t = blockIdx.x*1024 + tid; t < 33656; t += 16384) {
            if (t < 28672) {
                const int t2 = t >> 8, colx = t & 255;
                woPk[t] = packh2(w_out[(size_t)(2*t2)*DIM + colx],
                                 w_out[(size_t)(2*t2 + 1)*DIM + colx]);
            } else if (t < 31808) {
                const int v = t - 28672, f2 = v / 56, cx = v % 56;
                wp2[v] = packh2(w_pair[(2*f2)*PAIR_CN + cx],
                                w_pair[(2*f2 + 1)*PAIR_CN + cx]);
            } else {
                const int v = t - 31808, r2 = v / 56, cx = v % 56;
                remb2[v] = packh2(remb[(2*r2)*PAIR_CN + cx],
                                  remb[(2*r2 + 1)*PAIR_CN + cx]);
            }
        }
    }

    if (tid < 512) {
        const int r = tid >> 8, d = tid & 255;
        xL[r][d] = local[(size_t)(i0 + r) * DIM + d];
    }
    if (tid >= 512 && tid < 896) wbS[tid - 512] = w_bias[tid - 512];
    __syncthreads();

    const int cstBF = ((i0 >> 5) << 8) + (((i0 >> 3) & 3) << 6) + ((i0 >> 1) & 3);

    if (tid < 672) {
        const int colg = tid >> 2, dq = tid & 3;
        const int col = colg * 4;
        const float* w; int width, c, seg;
        if      (col < 128) { w = w_q;  c = col;       width = 128; seg = 0; }
        else if (col < 256) { w = w_k;  c = col - 128; width = 128; seg = 1; }
        else if (col < 384) { w = w_v;  c = col - 256; width = 128; seg = 2; }
        else if (col < 480) { w = w_qp; c = col - 384; width = 96;  seg = 3; }
        else if (col < 576) { w = w_kp; c = col - 480; width = 96;  seg = 4; }
        else                { w = w_vp; c = col - 576; width = 96;  seg = 5; }

        float acc[2][4] = {{0.f,0.f,0.f,0.f},{0.f,0.f,0.f,0.f}};
        const float* wc = w + c;
        const int dbase = dq * 64;
#pragma unroll 1
        for (int bb = 0; bb < 8; ++bb) {
            const int d0 = dbase + bb*8;
            const float4 wv0 = *(const float4*)(wc + (size_t)(d0 + 0)*width);
            const float4 wv1 = *(const float4*)(wc + (size_t)(d0 + 1)*width);
            const float4 wv2 = *(const float4*)(wc + (size_t)(d0 + 2)*width);
            const float4 wv3 = *(const float4*)(wc + (size_t)(d0 + 3)*width);
            const float4 wv4 = *(const float4*)(wc + (size_t)(d0 + 4)*width);
            const float4 wv5 = *(const float4*)(wc + (size_t)(d0 + 5)*width);
            const float4 wv6 = *(const float4*)(wc + (size_t)(d0 + 6)*width);
            const float4 wv7 = *(const float4*)(wc + (size_t)(d0 + 7)*width);
#pragma unroll
            for (int r = 0; r < 2; ++r) {
                const float x0 = xL[r][d0 + 0], x1 = xL[r][d0 + 1];
                const float x2 = xL[r][d0 + 2], x3 = xL[r][d0 + 3];
                const float x4 = xL[r][d0 + 4], x5 = xL[r][d0 + 5];
                const float x6 = xL[r][d0 + 6], x7 = xL[r][d0 + 7];
                acc[r][0] += x0*wv0.x + x1*wv1.x + x2*wv2.x + x3*wv3.x
                           + x4*wv4.x + x5*wv5.x + x6*wv6.x + x7*wv7.x;
                acc[r][1] += x0*wv0.y + x1*wv1.y + x2*wv2.y + x3*wv3.y
                           + x4*wv4.y + x5*wv5.y + x6*wv6.y + x7*wv7.y;
                acc[r][2] += x0*wv0.z + x1*wv1.z + x2*wv2.z + x3*wv3.z
                           + x4*wv4.z + x5*wv5.z + x6*wv6.z + x7*wv7.z;
                acc[r][3] += x0*wv0.w + x1*wv1.w + x2*wv2.w + x3*wv3.w
                           + x4*wv4.w + x5*wv5.w + x6*wv6.w + x7*wv7.w;
            }
        }
#pragma unroll
        for (int r = 0; r < 2; ++r)
#pragma unroll
            for (int e = 0; e < 4; ++e) {
                acc[r][e] += __shfl_xor(acc[r][e], 1);
                acc[r][e] += __shfl_xor(acc[r][e], 2);
            }

        if (dq == 0) {
            const float cax0 = pos[i0*15+3],     cay0 = pos[i0*15+4],     caz0 = pos[i0*15+5];
            const float cax1 = pos[(i0+1)*15+3], cay1 = pos[(i0+1)*15+4], caz1 = pos[(i0+1)*15+5];
            float fr0[4], fr1[4];
            const bool isKp = (seg == 4), isQp = (seg == 3);
#pragma unroll
            for (int e = 0; e < 4; ++e) {
                const int cc = c + e;
                const float v0 = acc[0][e], v1 = acc[1][e];
                if (seg == 0) {
                    qraw[0][cc] = v0 + b_q[cc];
                    qraw[1][cc] = v1 + b_q[cc];
                } else if (seg == 1) {
                    kraw[0][cc] = v0 + b_k[cc];
                    kraw[1][cc] = v1 + b_k[cc];
                } else if (seg == 2) {
                    const int h = cc >> 5, sc = cc & 31;
                    const int colF = h*PAIR_CN + sc;
                    BF[(colF >> 4)*4096 + (colF & 15)*4 + cstBF] =
                        packh2(v0 + b_v[cc], v1 + b_v[cc]);
                } else if (seg == 3) {
                    const int x = cc % 3;
                    const float cav0 = (x==0)?cax0:((x==1)?cay0:caz0);
                    const float cav1 = (x==0)?cax1:((x==1)?cay1:caz1);
                    const float r0 = v0 + b_qp[cc] + cav0;
                    const float r1 = v1 + b_qp[cc] + cav1;
                    fr0[e] = r0; fr1[e] = r1;
                    qpL[0][cc] = r0; qpL[1][cc] = r1;
                } else if (seg == 4) {
                    const int x = cc % 3;
                    const float cav0 = (x==0)?cax0:((x==1)?cay0:caz0);
                    const float cav1 = (x==0)?cax1:((x==1)?cay1:caz1);
                    const float r0 = v0 + b_kp[cc] + cav0;
                    const float r1 = v1 + b_kp[cc] + cav1;
                    fr0[e] = r0; fr1[e] = r1;
                    const int colF = 224 + cc;
                    BF[(colF >> 4)*4096 + (colF & 15)*4 + cstBF] = packh2(r0, r1);
                    kpbL[0][cc] = (float)(_Float16)r0;
                    kpbL[1][cc] = (float)(_Float16)r1;
                } else {
                    const int h = cc / 24, rr = cc % 24, x = cc % 3;
                    const float cav0 = (x==0)?cax0:((x==1)?cay0:caz0);
                    const float cav1 = (x==0)?cax1:((x==1)?cay1:caz1);
                    const int colF = h*PAIR_CN + 32 + rr;
                    BF[(colF >> 4)*4096 + (colF & 15)*4 + cstBF] =
                        packh2(v0 + b_vp[cc] + cav0, v1 + b_vp[cc] + cav1);
                }
            }
            if (isQp) {
                const int f2 = c >> 1;
                qpP[(size_t)i0*48 + f2]         = packh2(fr0[0], fr0[1]);
                qpP[(size_t)i0*48 + f2 + 1]     = packh2(fr0[2], fr0[3]);
                qpP[(size_t)(i0+1)*48 + f2]     = packh2(fr1[0], fr1[1]);
                qpP[(size_t)(i0+1)*48 + f2 + 1] = packh2(fr1[2], fr1[3]);
            }
            if (isKp) {
                const int f2 = c >> 1;
                const int fq = f2 >> 2;
                kpT4[((size_t)fq*N_NODES + i0    )*4 + (f2 & 3)]       = packh2(fr0[0], fr0[1]);
                kpT4[((size_t)fq*N_NODES + i0    )*4 + ((f2 + 1) & 3)] = packh2(fr0[2], fr0[3]);
                kpT4[((size_t)fq*N_NODES + i0 + 1)*4 + (f2 & 3)]       = packh2(fr1[0], fr1[1]);
                kpT4[((size_t)fq*N_NODES + i0 + 1)*4 + ((f2 + 1) & 3)] = packh2(fr1[2], fr1[3]);
            }
        }
    }
    __syncthreads();

    if (tid < 16) {
        const int r = tid >> 3, t = tid & 7;
        const float* src = (t < 4) ? qraw[r] : kraw[r];
        const int h = t & 3, base = (t < 4) ? 0 : 8;
        float mu = 0.f;
        for (int c = 0; c < 32; ++c) mu += src[h*32 + c];
        mu *= (1.f/32.f);
        float var = 0.f;
        for (int c = 0; c < 32; ++c) { float d = src[h*32 + c] - mu; var += d*d; }
        var *= (1.f/32.f);
        stat[r][base + h*2 + 0] = mu;
        stat[r][base + h*2 + 1] = var;
    }
    __syncthreads();

    if (tid < 512) {
        const int r = tid >> 8, u = tid & 255;
        const int i = i0 + r;
        if (u < 128) {
            const int h = u >> 5, sidx = u & 31;
            const float mu = stat[r][h*2], var = stat[r][h*2+1];
            float v = (qraw[r][u] - mu) * rsqrtf(var + 1e-5f) * qls[sidx] + qlo[sidx];
            v *= 0.17677669529663687f;  // * sqrt(1/S)
            const float vo = __shfl_xor(v, 1);
            if (!(u & 1)) qnP[(size_t)i*64 + (u >> 1)] = packh2(v, vo);
        } else {
            const int u2 = u - 128, h = u2 >> 5, sidx = u2 & 31;
            const float mu = stat[r][8 + h*2], var = stat[r][9 + h*2];
            float v = (kraw[r][u2] - mu) * rsqrtf(var + 1e-5f) * kls[sidx] + klo[sidx];
            const float vo = __shfl_xor(v, 1);
            if (!(u2 & 1))
                knT4[(((size_t)(u2 >> 3))*N_NODES + i)*4 + ((u2 >> 1) & 3)] = packh2(v, vo);
        }
    }

    if (tid < 64) {
        const int r = tid >> 5, h = (tid >> 3) & 3, ks = tid & 7;
        float uacc = 0.f, tacc = 0.f;
#pragma unroll
        for (int f = ks; f < P3_N; f += 8) {
            float wb = wbS[f*4 + h];
            uacc += qpL[r][f] * wb;
            tacc += kpbL[r][f] * wb;
        }
        float nq = 0.f, nk = 0.f;
#pragma unroll
        for (int f = h*24 + ks*3; f < h*24 + ks*3 + 3; ++f) {
            nq += qpL[r][f]*qpL[r][f];
            nk += kpbL[r][f]*kpbL[r][f];
        }
        uacc += __shfl_xor(uacc,1); uacc += __shfl_xor(uacc,2); uacc += __shfl_xor(uacc,4);
        tacc += __shfl_xor(tacc,1); tacc += __shfl_xor(tacc,2); tacc += __shfl_xor(tacc,4);
        nq   += __shfl_xor(nq,1);   nq   += __shfl_xor(nq,2);   nq   += __shfl_xor(nq,4);
        nk   += __shfl_xor(nk,1);   nk   += __shfl_xor(nk,2);   nk   += __shfl_xor(nk,4);
        if (ks == 0) {
            const int n = i0 + r;
            const float ps = log1pf(expf(gamma[h])) * (1.0f/12.0f);
            iinfo[n*4 + h] = -ps*nq + uacc + b_bias[h];
            jinfo[n*8 + h] = -ps*nk - tacc;
            if (h == 0) {
                jinfo[n*8 + 4] = 10.f * pos[n*15 + 3];
                jinfo[n*8 + 5] = 10.f * pos[n*15 + 4];
                jinfo[n*8 + 6] = 10.f * pos[n*15 + 5];
                jinfo[n*8 + 7] = 0.f;
            }
        }
    }

    // =====================================================================
    // GRID BARRIER (all 256 blocks co-resident; device-scope fences)
    // =====================================================================
    __threadfence();
    __syncthreads();
    if (tid == 0) {
        atomicAdd(barCnt, 1u);
        while (__hip_atomic_load(barCnt, __ATOMIC_ACQUIRE,
                                 __HIP_MEMORY_SCOPE_AGENT) < (unsigned)gridDim.x) {
            __builtin_amdgcn_s_sleep(1);
        }
    }
    __syncthreads();
    __threadfence();

    // =====================================================================
    // ATTN PHASE (round 17 body)
    // =====================================================================
    const int lane = tid & 63;
    const int wv   = tid >> 6;
    const int hp   = tid >> 9;
    const int j    = tid & 511;

    if (tid < 128) {
        const int r = tid >> 6, u = tid & 63;
        qpkL[r][u] = qnP[(size_t)(ib + r)*64 + u];
    } else if (tid < 224) {
        const int v = tid - 128, r = v / 48, f2 = v % 48;
        const int h = f2 / 12;
        const float ps2 = 2.f * log1pf(expf(gamma[h])) * (1.0f/12.0f);
        const unsigned u = qpP[(size_t)(ib + r)*48 + f2];
        qspkL[r][f2] = packh2(ps2*h2lof(u), ps2*h2hif(u));
    } else if (tid < 320) {
        const int v = tid - 224, r = v / 48, f2 = v % 48;
        const unsigned u = qpP[(size_t)(ib + r)*48 + f2];
        qpiL2[r][2*f2]   = h2lof(u);
        qpiL2[r][2*f2+1] = h2hif(u);
    } else if (tid < 352) {
        const int v = tid - 320, h = v >> 3, e = v & 7;
        wbPk[h][e] = packh2(w_bias[(P3_N + 2*e)*H_HEADS + h],
                            w_bias[(P3_N + 2*e + 1)*H_HEADS + h]);
    }
    for (int t = tid; t < 8*2*H_HEADS*66; t += 1024) ((float*)abktW8)[t] = 0.f;

    const int  ri0 = resi[ib], ri1 = resi[ib+1];
    const int  ch0 = chain[ib], ch1 = chain[ib+1];
    const int  ba0 = batch[ib], ba1 = batch[ib+1];
    const bool mi0 = mask_true(maskp, ib), mi1 = mask_true(maskp, ib+1);
    const float dix0 = jinfo[(size_t)ib*8+4], diy0 = jinfo[(size_t)ib*8+5], diz0 = jinfo[(size_t)ib*8+6];
    const float dix1 = jinfo[(size_t)(ib+1)*8+4], diy1 = jinfo[(size_t)(ib+1)*8+5], diz1 = jinfo[(size_t)(ib+1)*8+6];

    const float inv3  = 0.57735026918962576f;
    const float rstep = 0.72727272727272727f;   // 1/1.375

    const float4 vq4 = *(const float4*)(jinfo + (size_t)j*8);
    const float4 dj4 = *(const float4*)(jinfo + (size_t)j*8 + 4);
    const float4 ciA = *(const float4*)(iinfo + (size_t)ib*4);
    const float4 ciB = *(const float4*)(iinfo + (size_t)(ib+1)*4);
    const float vqa[4] = {vq4.x, vq4.y, vq4.z, vq4.w};
    const float cia[2][4] = {{ciA.x, ciA.y, ciA.z, ciA.w},
                             {ciB.x, ciB.y, ciB.z, ciB.w}};
    {
        const float dx = (hp ? dix1 : dix0) - dj4.x;
        const float dy = (hp ? diy1 : diy0) - dj4.y;
        const float dz = (hp ? diz1 : diz0) - dj4.z;
        const float dist = sqrtf(dx*dx + dy*dy + dz*dz + 1e-6f);
#pragma unroll
        for (int p = 0; p < 8; ++p) {
            const float u0 = (dist - (1.375f*(float)(2*p)   + 0.6875f)) * rstep;
            const float u1 = (dist - (1.375f*(float)(2*p+1) + 0.6875f)) * rstep;
            rbfP[hp][j][p] = packh2(__expf(-u0*u0), __expf(-u1*u1));
        }
    }
    const int  rj = resi[j], cj = chain[j], bj = batch[j];
    const bool mj = mask_true(maskp, j);
    bool pmv[2];
    int  rdv[2];
    pmv[0] = mi0 && mj && (ba0 == bj);
    pmv[1] = mi1 && mj && (ba1 == bj);
    rdv[0] = (ch0 != cj) ? 65 : (min(max(ri0 - rj, -32), 32) + 32);
    rdv[1] = (ch1 != cj) ? 65 : (min(max(ri1 - rj, -32), 32) + 32);
    __syncthreads();

    // Pass A
    float lv[2][2];
    {
        const int h0 = hp*2, h1 = hp*2 + 1;
        const uint4* kcol = (const uint4*)knT4 + j;
        const uint4* pcol = (const uint4*)kpT4 + j;
        const uint4 ka0 = kcol[(size_t)(h0*4 + 0)*N_NODES];
        const uint4 ka1 = kcol[(size_t)(h0*4 + 1)*N_NODES];
        const uint4 ka2 = kcol[(size_t)(h0*4 + 2)*N_NODES];
        const uint4 ka3 = kcol[(size_t)(h0*4 + 3)*N_NODES];
        const uint4 kb0 = kcol[(size_t)(h1*4 + 0)*N_NODES];
        const uint4 kb1 = kcol[(size_t)(h1*4 + 1)*N_NODES];
        const uint4 kb2 = kcol[(size_t)(h1*4 + 2)*N_NODES];
        const uint4 kb3 = kcol[(size_t)(h1*4 + 3)*N_NODES];
        const uint4 pa0 = pcol[(size_t)(h0*3 + 0)*N_NODES];
        const uint4 pa1 = pcol[(size_t)(h0*3 + 1)*N_NODES];
        const uint4 pa2 = pcol[(size_t)(h0*3 + 2)*N_NODES];
        const uint4 pb0 = pcol[(size_t)(h1*3 + 0)*N_NODES];
        const uint4 pb1 = pcol[(size_t)(h1*3 + 1)*N_NODES];
        const uint4 pb2 = pcol[(size_t)(h1*3 + 2)*N_NODES];
        const uint4 rr0a = *(const uint4*)&rbfP[0][j][0];
        const uint4 rr0b = *(const uint4*)&rbfP[0][j][4];
        const uint4 rr1a = *(const uint4*)&rbfP[1][j][0];
        const uint4 rr1b = *(const uint4*)&rbfP[1][j][4];
        const uint4 w0a = *(const uint4*)&wbPk[hp*2][0];
        const uint4 w0b = *(const uint4*)&wbPk[hp*2][4];
        const uint4 w1a = *(const uint4*)&wbPk[hp*2 + 1][0];
        const uint4 w1b = *(const uint4*)&wbPk[hp*2 + 1][4];
#pragma unroll
        for (int r = 0; r < 2; ++r) {
            const uint4* qk4 = (const uint4*)&qpkL[r][0];
            const uint4* qs4 = (const uint4*)&qspkL[r][0];
            const uint4 rra = r ? rr1a : rr0a;
            const uint4 rrb = r ? rr1b : rr0b;
            float a0 = 0.f;
            {
                const uint4 q0 = qk4[h0*4 + 0], q1 = qk4[h0*4 + 1];
                const uint4 q2 = qk4[h0*4 + 2], q3 = qk4[h0*4 + 3];
                a0 = dot2u(ka0.x, q0.x, a0); a0 = dot2u(ka0.y, q0.y, a0);
                a0 = dot2u(ka0.z, q0.z, a0); a0 = dot2u(ka0.w, q0.w, a0);
                a0 = dot2u(ka1.x, q1.x, a0); a0 = dot2u(ka1.y, q1.y, a0);
                a0 = dot2u(ka1.z, q1.z, a0); a0 = dot2u(ka1.w, q1.w, a0);
                a0 = dot2u(ka2.x, q2.x, a0); a0 = dot2u(ka2.y, q2.y, a0);
                a0 = dot2u(ka2.z, q2.z, a0); a0 = dot2u(ka2.w, q2.w, a0);
                a0 = dot2u(ka3.x, q3.x, a0); a0 = dot2u(ka3.y, q3.y, a0);
                a0 = dot2u(ka3.z, q3.z, a0); a0 = dot2u(ka3.w, q3.w, a0);
                const uint4 s0 = qs4[h0*3 + 0], s1 = qs4[h0*3 + 1], s2 = qs4[h0*3 + 2];
                a0 = dot2u(pa0.x, s0.x, a0); a0 = dot2u(pa0.y, s0.y, a0);
                a0 = dot2u(pa0.z, s0.z, a0); a0 = dot2u(pa0.w, s0.w, a0);
                a0 = dot2u(pa1.x, s1.x, a0); a0 = dot2u(pa1.y, s1.y, a0);
                a0 = dot2u(pa1.z, s1.z, a0); a0 = dot2u(pa1.w, s1.w, a0);
                a0 = dot2u(pa2.x, s2.x, a0); a0 = dot2u(pa2.y, s2.y, a0);
                a0 = dot2u(pa2.z, s2.z, a0); a0 = dot2u(pa2.w, s2.w, a0);
                a0 = dot2u(rra.x, w0a.x, a0); a0 = dot2u(rra.y, w0a.y, a0);
                a0 = dot2u(rra.z, w0a.z, a0); a0 = dot2u(rra.w, w0a.w, a0);
                a0 = dot2u(rrb.x, w0b.x, a0); a0 = dot2u(rrb.y, w0b.y, a0);
                a0 = dot2u(rrb.z, w0b.z, a0); a0 = dot2u(rrb.w, w0b.w, a0);
            }
            lv[r][0] = pmv[r] ? (a0 + cia[r][h0] + vqa[h0]) * inv3 : -1e9f;
            float a1 = 0.f;
            {
                const uint4 q0 = qk4[h1*4 + 0], q1 = qk4[h1*4 + 1];
                const uint4 q2 = qk4[h1*4 + 2], q3 = qk4[h1*4 + 3];
                a1 = dot2u(kb0.x, q0.x, a1); a1 = dot2u(kb0.y, q0.y, a1);
                a1 = dot2u(kb0.z, q0.z, a1); a1 = dot2u(kb0.w, q0.w, a1);
                a1 = dot2u(kb1.x, q1.x, a1); a1 = dot2u(kb1.y, q1.y, a1);
                a1 = dot2u(kb1.z, q1.z, a1); a1 = dot2u(kb1.w, q1.w, a1);
                a1 = dot2u(kb2.x, q2.x, a1); a1 = dot2u(kb2.y, q2.y, a1);
                a1 = dot2u(kb2.z, q2.z, a1); a1 = dot2u(kb2.w, q2.w, a1);
                a1 = dot2u(kb3.x, q3.x, a1); a1 = dot2u(kb3.y, q3.y, a1);
                a1 = dot2u(kb3.z, q3.z, a1); a1 = dot2u(kb3.w, q3.w, a1);
                const uint4 s0 = qs4[h1*3 + 0], s1 = qs4[h1*3 + 1], s2 = qs4[h1*3 + 2];
                a1 = dot2u(pb0.x, s0.x, a1); a1 = dot2u(pb0.y, s0.y, a1);
                a1 = dot2u(pb0.z, s0.z, a1); a1 = dot2u(pb0.w, s0.w, a1);
                a1 = dot2u(pb1.x, s1.x, a1); a1 = dot2u(pb1.y, s1.y, a1);
                a1 = dot2u(pb1.z, s1.z, a1); a1 = dot2u(pb1.w, s1.w, a1);
                a1 = dot2u(pb2.x, s2.x, a1); a1 = dot2u(pb2.y, s2.y, a1);
                a1 = dot2u(pb2.z, s2.z, a1); a1 = dot2u(pb2.w, s2.w, a1);
                a1 = dot2u(rra.x, w1a.x, a1); a1 = dot2u(rra.y, w1a.y, a1);
                a1 = dot2u(rra.z, w1a.z, a1); a1 = dot2u(rra.w, w1a.w, a1);
                a1 = dot2u(rrb.x, w1b.x, a1); a1 = dot2u(rrb.y, w1b.y, a1);
                a1 = dot2u(rrb.z, w1b.z, a1); a1 = dot2u(rrb.w, w1b.w, a1);
            }
            lv[r][1] = pmv[r] ? (a1 + cia[r][h1] + vqa[h1]) * inv3 : -1e9f;
        }
    }

    // Softmax
    {
        float mx[4] = {lv[0][0], lv[0][1], lv[1][0], lv[1][1]};
#pragma unroll
        for (int off = 1; off < 64; off <<= 1) {
#pragma unroll
            for (int s = 0; s < 4; ++s) mx[s] = fmaxf(mx[s], __shfl_xor(mx[s], off));
        }
        if (lane == 0) *(float4*)&mxW[wv][0] = make_float4(mx[0], mx[1], mx[2], mx[3]);
        __syncthreads();
        float mxg[4] = {-1e30f, -1e30f, -1e30f, -1e30f};
        const int wbase = hp*8;
#pragma unroll
        for (int w = 0; w < 8; ++w) {
            const float4 m = *(const float4*)&mxW[wbase + w][0];
            mxg[0] = fmaxf(mxg[0], m.x); mxg[1] = fmaxf(mxg[1], m.y);
            mxg[2] = fmaxf(mxg[2], m.z); mxg[3] = fmaxf(mxg[3], m.w);
        }
        float e[4], sm[4];
        e[0] = pmv[0] ? __expf(lv[0][0] - mxg[0]) : 0.f;
        e[1] = pmv[0] ? __expf(lv[0][1] - mxg[1]) : 0.f;
        e[2] = pmv[1] ? __expf(lv[1][0] - mxg[2]) : 0.f;
        e[3] = pmv[1] ? __expf(lv[1][1] - mxg[3]) : 0.f;
#pragma unroll
        for (int s = 0; s < 4; ++s) sm[s] = e[s];
#pragma unroll
        for (int off = 1; off < 64; off <<= 1) {
#pragma unroll
            for (int s = 0; s < 4; ++s) sm[s] += __shfl_xor(sm[s], off);
        }
        if (lane == 0) *(float4*)&smW[wv][0] = make_float4(sm[0], sm[1], sm[2], sm[3]);
        __syncthreads();
        float smt[4] = {0.f, 0.f, 0.f, 0.f};
#pragma unroll
        for (int w = 0; w < 8; ++w) {
            const float4 m = *(const float4*)&smW[wbase + w][0];
            smt[0] += m.x; smt[1] += m.y; smt[2] += m.z; smt[3] += m.w;
        }
        float p[4];
#pragma unroll
        for (int s = 0; s < 4; ++s) {
            const float rden = 1.f / fmaxf(smt[s], 1e-37f);
            p[s] = e[s] * rden;
        }
        const int h0 = hp*2;
        atomicAdd(&abktW8[wv & 7][0][h0    ][rdv[0]], p[0]);
        atomicAdd(&abktW8[wv & 7][0][h0 + 1][rdv[0]], p[1]);
        atomicAdd(&abktW8[wv & 7][1][h0    ][rdv[1]], p[2]);
        atomicAdd(&abktW8[wv & 7][1][h0 + 1][rdv[1]], p[3]);
        if (j == 0) {
            asL2[0][h0]     = smt[0] / fmaxf(smt[0], 1e-37f);
            asL2[0][h0 + 1] = smt[1] / fmaxf(smt[1], 1e-37f);
            asL2[1][h0]     = smt[2] / fmaxf(smt[2], 1e-37f);
            asL2[1][h0 + 1] = smt[3] / fmaxf(smt[3], 1e-37f);
        }
#pragma unroll
        for (int s = 0; s < 4; ++s) {
            const float po = __shfl_xor(p[s], 1);
            if (!(j & 1)) {
                const int r = s >> 1, hh = s & 1;
                attnH2[r*4 + h0 + hh][j >> 1] = packh2(p[s], po);
            }
        }
    }
    __syncthreads();

    // Pass B
    if (wv < 14) {
        const int row = lane & 15;
        const int ntA = wv;
        const int ntB = (wv < 6) ? (wv + 14) : -1;
        f32x4 accA = {0.f,0.f,0.f,0.f};
        f32x4 accB = {0.f,0.f,0.f,0.f};
        const uint4* bfp = (const uint4*)BF;
#pragma unroll 4
        for (int kt = 0; kt < 16; ++kt) {
            uint4 au = make_uint4(0u, 0u, 0u, 0u);
            if (row < 8) au = *(const uint4*)&attnH2[row][kt*16 + (lane >> 4)*4];
            const uint4 bA = bfp[(ntA*16 + kt)*64 + lane];
            accA = mfma16(au, bA, accA);
            if (ntB >= 0) {
                const uint4 bB = bfp[(ntB*16 + kt)*64 + lane];
                accB = mfma16(au, bB, accB);
            }
        }
        if (lane < 32) {
            const int r = lane >> 4, c16 = lane & 15;
            {
                const int s = ntA*16 + c16;
                if (s < HPC) {
                    resL2[r][s] = ((const float*)&accA)[s / PAIR_CN];
                } else {
                    const int f = s - HPC;
                    GLfF2[r][0][f] = accA[0];
                    GLfF2[r][1][f] = accA[1];
                    GLfF2[r][2][f] = accA[2];
                    GLfF2[r][3][f] = accA[3];
                }
            }
            if (ntB >= 0) {
                const int s = ntB*16 + c16;
                if (s < HPC) {
                    resL2[r][s] = ((const float*)&accB)[s / PAIR_CN];
                } else {
                    const int f = s - HPC;
                    GLfF2[r][0][f] = accB[0];
                    GLfF2[r][1][f] = accB[1];
                    GLfF2[r][2][f] = accB[2];
                    GLfF2[r][3][f] = accB[3];
                }
            }
        }
    } else {
        const int r = wv - 14;
        const int b = lane >> 2, q = lane & 3;
        const int w = b >> 1;
        const bool hi = (b & 1);
        float a[4] = {0.f, 0.f, 0.f, 0.f};
#pragma unroll 4
        for (int jpp = q*64; jpp < q*64 + 64; ++jpp) {
            const unsigned r0 = rbfP[r][2*jpp][w];
            const unsigned r1 = rbfP[r][2*jpp + 1][w];
            const unsigned ee = hi ? ((r0 >> 16) | (r1 & 0xffff0000u))
                                   : ((r0 & 0xffffu) | (r1 << 16));
            a[0] = dot2u(ee, attnH2[r*4 + 0][jpp], a[0]);
            a[1] = dot2u(ee, attnH2[r*4 + 1][jpp], a[1]);
            a[2] = dot2u(ee, attnH2[r*4 + 2][jpp], a[2]);
            a[3] = dot2u(ee, attnH2[r*4 + 3][jpp], a[3]);
        }
#pragma unroll
        for (int h = 0; h < 4; ++h) {
            a[h] += __shfl_xor(a[h], 1);
            a[h] += __shfl_xor(a[h], 2);
            if (q == 0) GLfR2[r][h][b] = a[h];
        }
    }
    __syncthreads();

    // Combine
    for (int t = tid; t < 448; t += 1024) {
        const int r = t / 224, v = t % 224, h = v / 56, f2 = v % 56;
        if (f2 < 48) {
            GLf22[r][h][f2] = packh2(qpiL2[r][2*f2]*asL2[r][h]     - GLfF2[r][h][2*f2],
                                     qpiL2[r][2*f2 + 1]*asL2[r][h] - GLfF2[r][h][2*f2 + 1]);
        } else {
            GLf22[r][h][f2] = packh2(GLfR2[r][h][(f2 - 48)*2], GLfR2[r][h][(f2 - 48)*2 + 1]);
        }
    }
    for (int t = tid; t < 264; t += 1024) {
        const int r = t / 132, v = t % 132, h = v / 33, r2 = v % 33;
        float s0 = 0.f, s1 = 0.f;
#pragma unroll
        for (int w = 0; w < 8; ++w) {
            s0 += abktW8[w][r][h][2*r2];
            s1 += abktW8[w][r][h][2*r2 + 1];
        }
        abktP2[r][h][r2] = packh2(s0, s1);
    }
    __syncthreads();

    // Epilogue
    if (tid < HPC) {
        const int h = tid / PAIR_CN, c = tid - h*PAIR_CN;
        float r0 = resL2[0][tid];
        float r1 = resL2[1][tid];
        {
            unsigned buf[16];
#pragma unroll
            for (int t = 0; t < 16; ++t) buf[t] = remb2[t*56 + c];
#pragma unroll
            for (int t = 0; t < 16; ++t) {
                r0 = dot2u(buf[t], abktP2[0][h][t], r0);
                r1 = dot2u(buf[t], abktP2[1][h][t], r1);
            }
#pragma unroll
            for (int t = 0; t < 16; ++t) buf[t] = remb2[(16 + t)*56 + c];
#pragma unroll
            for (int t = 0; t < 16; ++t) {
                r0 = dot2u(buf[t], abktP2[0][h][16 + t], r0);
                r1 = dot2u(buf[t], abktP2[1][h][16 + t], r1);
            }
            const unsigned b32 = remb2[32*56 + c];
            r0 = dot2u(b32, abktP2[0][h][32], r0);
            r1 = dot2u(b32, abktP2[1][h][32], r1);
        }
        {
            unsigned buf[14];
#pragma unroll
            for (int qq = 0; qq < 4; ++qq) {
#pragma unroll
                for (int t = 0; t < 14; ++t) buf[t] = wp2[(qq*14 + t)*56 + c];
#pragma unroll
                for (int t = 0; t < 14; ++t) {
                    r0 = dot2u(buf[t], GLf22[0][h][qq*14 + t], r0);
                    r1 = dot2u(buf[t], GLf22[1][h][qq*14 + t], r1);
                }
            }
        }
        resL2[0][tid] = r0;
        resL2[1][tid] = r1;
    }
    __syncthreads();

    if (tid < 2*FD_N) {
        const int r = tid / FD_N, t2 = tid % FD_N;
        resH2[r][t2] = packh2(resL2[r][2*t2], resL2[r][2*t2 + 1]);
    }
    __syncthreads();

    if (tid < 512) {
        const int col = tid >> 1, ph = tid & 1;
        float o0 = 0.f, o1 = 0.f;
        unsigned buf[14];
#pragma unroll
        for (int qq = 0; qq < 4; ++qq) {
            const int base = ph*56 + qq*14;
#pragma unroll
            for (int t = 0; t < 14; ++t) buf[t] = woPk[(base + t)*256 + col];
#pragma unroll
            for (int t = 0; t < 14; ++t) {
                o0 = dot2u(buf[t], resH2[0][base + t], o0);
                o1 = dot2u(buf[t], resH2[1][base + t], o1);
            }
        }
        o0 += __shfl_xor(o0, 1);
        o1 += __shfl_xor(o1, 1);
        if (ph == 0) {
            out[(size_t)ib*DIM + col]       = o0;
            out[(size_t)(ib + 1)*DIM + col] = o1;
        }
    }
}

// ---------------------------------------------------------------------------
extern "C" void kernel_launch(void* const* d_in, const int* in_sizes, int n_in,
                              void* d_out, int out_size, void* d_ws, size_t ws_size,
                              hipStream_t stream) {
    (void)in_sizes; (void)n_in; (void)out_size; (void)ws_size;
    const float* local = (const float*)d_in[0];
    const float* pos   = (const float*)d_in[1];
    const int*   resi  = (const int*)d_in[2];
    const int*   chain = (const int*)d_in[3];
    const int*   batch = (const int*)d_in[4];
    const void*  maskp = d_in[5];
    const float* qls   = (const float*)d_in[6];
    const float* qlo   = (const float*)d_in[7];
    const float* kls   = (const float*)d_in[8];
    const float* klo   = (const float*)d_in[9];
    const float* w_q   = (const float*)d_in[10];
    const float* b_q   = (const float*)d_in[11];
    const float* w_k   = (const float*)d_in[12];
    const float* b_k   = (const float*)d_in[13];
    const float* w_v   = (const float*)d_in[14];
    const float* b_v   = (const float*)d_in[15];
    const float* w_qp  = (const float*)d_in[16];
    const float* b_qp  = (const float*)d_in[17];
    const float* w_kp  = (const float*)d_in[18];
    const float* b_kp  = (const float*)d_in[19];
    const float* w_vp  = (const float*)d_in[20];
    const float* b_vp  = (const float*)d_in[21];
    const float* remb  = (const float*)d_in[22];
    const float* w_pair= (const float*)d_in[23];
    const float* w_bias= (const float*)d_in[24];
    const float* b_bias= (const float*)d_in[25];
    const float* gamma = (const float*)d_in[26];
    const float* w_out = (const float*)d_in[27];

    char* ws = (char*)d_ws;
    unsigned* qnP   = (unsigned*)(ws);            // 131072 B [512][64]
    unsigned* qpP   = (unsigned*)(ws + 131072);   //  98304 B [512][48]
    unsigned* knT4  = (unsigned*)(ws + 229376);   // 131072 B [16][512][4]
    unsigned* kpT4  = (unsigned*)(ws + 360448);   //  98304 B [12][512][4]
    unsigned* BF    = (unsigned*)(ws + 458752);   // 327680 B [20][16][64][4]
    float*    jinf  = (float*)(ws + 786432);      //  16384 B
    float*    iinf  = (float*)(ws + 802816);      //   8192 B
    unsigned* woPk  = (unsigned*)(ws + 811008);   // 114688 B [112][256]
    unsigned* wp2   = (unsigned*)(ws + 925696);   //  12544 B [56][56]
    unsigned* remb2 = (unsigned*)(ws + 938240);   //   7392 B [33][56]
    unsigned* barC  = (unsigned*)(ws + 945664);   //      4 B barrier counter

    hipMemsetAsync(barC, 0, 4, stream);

    fused_kernel<<<N_NODES / 2, 1024, 0, stream>>>(
        local, pos, qls, qlo, kls, klo,
        w_q, b_q, w_k, b_k, w_v, b_v,
        w_qp, b_qp, w_kp, b_kp, w_vp, b_vp,
        w_bias, b_bias, gamma,
        remb, w_pair, w_out,
        resi, chain, batch, maskp,
        qnP, knT4, qpP, kpT4, BF,
        woPk, wp2, remb2, jinf, iinf,
        barC,
        (float*)d_out);
}

// Round 19
// 53.788 us; speedup vs baseline: 3.7449x; 3.7449x over previous
//
#include <hip/hip_runtime.h>
#include <hip/hip_bf16.h>
#include <cstddef>

// Problem constants (N, D, S, H, QP, VP) = (512, 256, 32, 4, 8, 8)
#define N_NODES 512
#define DIM     256
#define H_HEADS 4
#define PAIR_CN 56    // S + 3*VP
#define P3_N    96    // H*QP*3
#define FD_N    112   // P3 + 16
#define HPC     224   // H * PAIR_C

typedef _Float16 h2v  __attribute__((ext_vector_type(2)));
typedef _Float16 f16x8 __attribute__((ext_vector_type(8)));
typedef float    f32x4 __attribute__((ext_vector_type(4)));

__device__ __forceinline__ bool mask_true(const void* m, int idx) {
    if (((const unsigned char*)m)[idx] != 0) return true;
    return ((const int*)m)[idx] != 0;
}
__device__ __forceinline__ unsigned packh2(float a, float b) {
    _Float16 ha = (_Float16)a, hb = (_Float16)b;
    unsigned short ua, ub;
    __builtin_memcpy(&ua, &ha, 2); __builtin_memcpy(&ub, &hb, 2);
    return (unsigned)ua | ((unsigned)ub << 16);
}
__device__ __forceinline__ float h2lof(unsigned u) {
    unsigned short t = (unsigned short)(u & 0xffff);
    _Float16 h; __builtin_memcpy(&h, &t, 2); return (float)h;
}
__device__ __forceinline__ float h2hif(unsigned u) {
    unsigned short t = (unsigned short)(u >> 16);
    _Float16 h; __builtin_memcpy(&h, &t, 2); return (float)h;
}
__device__ __forceinline__ float dot2u(unsigned a, unsigned b, float c) {
#if __has_builtin(__builtin_amdgcn_fdot2)
    h2v ha, hb;
    __builtin_memcpy(&ha, &a, 4);
    __builtin_memcpy(&hb, &b, 4);
    return __builtin_amdgcn_fdot2(ha, hb, c, false);
#else
    return c + h2lof(a)*h2lof(b) + h2hif(a)*h2hif(b);
#endif
}
__device__ __forceinline__ f32x4 mfma16(uint4 a, uint4 b, f32x4 c) {
    f16x8 af, bf;
    __builtin_memcpy(&af, &a, 16);
    __builtin_memcpy(&bf, &b, 16);
    return __builtin_amdgcn_mfma_f32_16x16x32_f16(af, bf, c, 0, 0, 0);
}

// ---------------------------------------------------------------------------
// Phase 1: projections + LayerNorm + separable terms + weight packing.
// ---------------------------------------------------------------------------
__global__ __launch_bounds__(512) void proj_kernel(
    const float* __restrict__ local, const float* __restrict__ pos,
    const float* __restrict__ qls, const float* __restrict__ qlo,
    const float* __restrict__ kls, const float* __restrict__ klo,
    const float* __restrict__ w_q, const float* __restrict__ b_q,
    const float* __restrict__ w_k, const float* __restrict__ b_k,
    const float* __restrict__ w_v, const float* __restrict__ b_v,
    const float* __restrict__ w_qp, const float* __restrict__ b_qp,
    const float* __restrict__ w_kp, const float* __restrict__ b_kp,
    const float* __restrict__ w_vp, const float* __restrict__ b_vp,
    const float* __restrict__ w_bias, const float* __restrict__ b_bias,
    const float* __restrict__ gamma,
    const float* __restrict__ remb, const float* __restrict__ w_pair,
    const float* __restrict__ w_out,
    unsigned* __restrict__ qnP, unsigned* __restrict__ knT4,
    unsigned* __restrict__ qpP, unsigned* __restrict__ kpT4,
    unsigned* __restrict__ BF,
    unsigned* __restrict__ woPk, unsigned* __restrict__ wp2,
    unsigned* __restrict__ remb2,
    float* __restrict__ jinfo, float* __restrict__ iinfo)
{
    const int i0 = blockIdx.x * 2;
    const int tid = threadIdx.x;

    __shared__ float xL[2][DIM];
    __shared__ float qraw[2][128];
    __shared__ float kraw[2][128];
    __shared__ float stat[2][16];
    __shared__ float qpL[2][P3_N];
    __shared__ float kpbL[2][P3_N];
    __shared__ float wbS[384];

    if (blockIdx.x < 16) {
        for (int t = blockIdx.x*512 + tid; t < 33656; t += 8192) {
            if (t < 28672) {
                const int t2 = t >> 8, colx = t & 255;
                woPk[t] = packh2(w_out[(size_t)(2*t2)*DIM + colx],
                                 w_out[(size_t)(2*t2 + 1)*DIM + colx]);
            } else if (t < 31808) {
                const int v = t - 28672, f2 = v / 56, cx = v % 56;
                wp2[v] = packh2(w_pair[(2*f2)*PAIR_CN + cx],
                                w_pair[(2*f2 + 1)*PAIR_CN + cx]);
            } else {
                const int v = t - 31808, r2 = v / 56, cx = v % 56;
                remb2[v] = packh2(remb[(2*r2)*PAIR_CN + cx],
                                  remb[(2*r2 + 1)*PAIR_CN + cx]);
            }
        }
    }

    {
        const int r = tid >> 8, d = tid & 255;
        xL[r][d] = local[(size_t)(i0 + r) * DIM + d];
    }
    if (tid < 384) wbS[tid] = w_bias[tid];
    __syncthreads();

    const int cstBF = ((i0 >> 5) << 8) + (((i0 >> 3) & 3) << 6) + ((i0 >> 1) & 3);

    if (tid < 336) {
        const int colg = tid >> 1, dh = tid & 1;
        const int col = colg * 4;
        const float* w; int width, c, seg;
        if      (col < 128) { w = w_q;  c = col;       width = 128; seg = 0; }
        else if (col < 256) { w = w_k;  c = col - 128; width = 128; seg = 1; }
        else if (col < 384) { w = w_v;  c = col - 256; width = 128; seg = 2; }
        else if (col < 480) { w = w_qp; c = col - 384; width = 96;  seg = 3; }
        else if (col < 576) { w = w_kp; c = col - 480; width = 96;  seg = 4; }
        else                { w = w_vp; c = col - 576; width = 96;  seg = 5; }

        float acc[2][4] = {{0.f,0.f,0.f,0.f},{0.f,0.f,0.f,0.f}};
        const float* wc = w + c;
        const int dbase = dh * 128;
#pragma unroll 1
        for (int bb = 0; bb < 16; ++bb) {
            const int d0 = dbase + bb*8;
            const float4 wv0 = *(const float4*)(wc + (size_t)(d0 + 0)*width);
            const float4 wv1 = *(const float4*)(wc + (size_t)(d0 + 1)*width);
            const float4 wv2 = *(const float4*)(wc + (size_t)(d0 + 2)*width);
            const float4 wv3 = *(const float4*)(wc + (size_t)(d0 + 3)*width);
            const float4 wv4 = *(const float4*)(wc + (size_t)(d0 + 4)*width);
            const float4 wv5 = *(const float4*)(wc + (size_t)(d0 + 5)*width);
            const float4 wv6 = *(const float4*)(wc + (size_t)(d0 + 6)*width);
            const float4 wv7 = *(const float4*)(wc + (size_t)(d0 + 7)*width);
#pragma unroll
            for (int r = 0; r < 2; ++r) {
                const float x0 = xL[r][d0 + 0], x1 = xL[r][d0 + 1];
                const float x2 = xL[r][d0 + 2], x3 = xL[r][d0 + 3];
                const float x4 = xL[r][d0 + 4], x5 = xL[r][d0 + 5];
                const float x6 = xL[r][d0 + 6], x7 = xL[r][d0 + 7];
                acc[r][0] += x0*wv0.x + x1*wv1.x + x2*wv2.x + x3*wv3.x
                           + x4*wv4.x + x5*wv5.x + x6*wv6.x + x7*wv7.x;
                acc[r][1] += x0*wv0.y + x1*wv1.y + x2*wv2.y + x3*wv3.y
                           + x4*wv4.y + x5*wv5.y + x6*wv6.y + x7*wv7.y;
                acc[r][2] += x0*wv0.z + x1*wv1.z + x2*wv2.z + x3*wv3.z
                           + x4*wv4.z + x5*wv5.z + x6*wv6.z + x7*wv7.z;
                acc[r][3] += x0*wv0.w + x1*wv1.w + x2*wv2.w + x3*wv3.w
                           + x4*wv4.w + x5*wv5.w + x6*wv6.w + x7*wv7.w;
            }
        }
#pragma unroll
        for (int r = 0; r < 2; ++r)
#pragma unroll
            for (int e = 0; e < 4; ++e)
                acc[r][e] += __shfl_xor(acc[r][e], 1);

        if (dh == 0) {
            const float cax0 = pos[i0*15+3],     cay0 = pos[i0*15+4],     caz0 = pos[i0*15+5];
            const float cax1 = pos[(i0+1)*15+3], cay1 = pos[(i0+1)*15+4], caz1 = pos[(i0+1)*15+5];
            float fr0[4], fr1[4];
            const bool isKp = (seg == 4), isQp = (seg == 3);
#pragma unroll
            for (int e = 0; e < 4; ++e) {
                const int cc = c + e;
                const float v0 = acc[0][e], v1 = acc[1][e];
                if (seg == 0) {
                    qraw[0][cc] = v0 + b_q[cc];
                    qraw[1][cc] = v1 + b_q[cc];
                } else if (seg == 1) {
                    kraw[0][cc] = v0 + b_k[cc];
                    kraw[1][cc] = v1 + b_k[cc];
                } else if (seg == 2) {
                    const int h = cc >> 5, sc = cc & 31;
                    const int colF = h*PAIR_CN + sc;
                    BF[(colF >> 4)*4096 + (colF & 15)*4 + cstBF] =
                        packh2(v0 + b_v[cc], v1 + b_v[cc]);
                } else if (seg == 3) {
                    const int x = cc % 3;
                    const float cav0 = (x==0)?cax0:((x==1)?cay0:caz0);
                    const float cav1 = (x==0)?cax1:((x==1)?cay1:caz1);
                    const float r0 = v0 + b_qp[cc] + cav0;
                    const float r1 = v1 + b_qp[cc] + cav1;
                    fr0[e] = r0; fr1[e] = r1;
                    qpL[0][cc] = r0; qpL[1][cc] = r1;
                } else if (seg == 4) {
                    const int x = cc % 3;
                    const float cav0 = (x==0)?cax0:((x==1)?cay0:caz0);
                    const float cav1 = (x==0)?cax1:((x==1)?cay1:caz1);
                    const float r0 = v0 + b_kp[cc] + cav0;
                    const float r1 = v1 + b_kp[cc] + cav1;
                    fr0[e] = r0; fr1[e] = r1;
                    const int colF = 224 + cc;
                    BF[(colF >> 4)*4096 + (colF & 15)*4 + cstBF] = packh2(r0, r1);
                    kpbL[0][cc] = (float)(_Float16)r0;
                    kpbL[1][cc] = (float)(_Float16)r1;
                } else {
                    const int h = cc / 24, rr = cc % 24, x = cc % 3;
                    const float cav0 = (x==0)?cax0:((x==1)?cay0:caz0);
                    const float cav1 = (x==0)?cax1:((x==1)?cay1:caz1);
                    const int colF = h*PAIR_CN + 32 + rr;
                    BF[(colF >> 4)*4096 + (colF & 15)*4 + cstBF] =
                        packh2(v0 + b_vp[cc] + cav0, v1 + b_vp[cc] + cav1);
                }
            }
            if (isQp) {
                const int f2 = c >> 1;
                qpP[(size_t)i0*48 + f2]         = packh2(fr0[0], fr0[1]);
                qpP[(size_t)i0*48 + f2 + 1]     = packh2(fr0[2], fr0[3]);
                qpP[(size_t)(i0+1)*48 + f2]     = packh2(fr1[0], fr1[1]);
                qpP[(size_t)(i0+1)*48 + f2 + 1] = packh2(fr1[2], fr1[3]);
            }
            if (isKp) {
                const int f2 = c >> 1;
                const int fq = f2 >> 2;
                kpT4[((size_t)fq*N_NODES + i0    )*4 + (f2 & 3)]       = packh2(fr0[0], fr0[1]);
                kpT4[((size_t)fq*N_NODES + i0    )*4 + ((f2 + 1) & 3)] = packh2(fr0[2], fr0[3]);
                kpT4[((size_t)fq*N_NODES + i0 + 1)*4 + (f2 & 3)]       = packh2(fr1[0], fr1[1]);
                kpT4[((size_t)fq*N_NODES + i0 + 1)*4 + ((f2 + 1) & 3)] = packh2(fr1[2], fr1[3]);
            }
        }
    }
    __syncthreads();

    if (tid < 16) {
        const int r = tid >> 3, t = tid & 7;
        const float* src = (t < 4) ? qraw[r] : kraw[r];
        const int h = t & 3, base = (t < 4) ? 0 : 8;
        float mu = 0.f;
        for (int c = 0; c < 32; ++c) mu += src[h*32 + c];
        mu *= (1.f/32.f);
        float var = 0.f;
        for (int c = 0; c < 32; ++c) { float d = src[h*32 + c] - mu; var += d*d; }
        var *= (1.f/32.f);
        stat[r][base + h*2 + 0] = mu;
        stat[r][base + h*2 + 1] = var;
    }
    __syncthreads();

    {
        const int r = tid >> 8, u = tid & 255;
        const int i = i0 + r;
        if (u < 128) {
            const int h = u >> 5, sidx = u & 31;
            const float mu = stat[r][h*2], var = stat[r][h*2+1];
            float v = (qraw[r][u] - mu) * rsqrtf(var + 1e-5f) * qls[sidx] + qlo[sidx];
            v *= 0.17677669529663687f;  // * sqrt(1/S)
            const float vo = __shfl_xor(v, 1);
            if (!(u & 1)) qnP[(size_t)i*64 + (u >> 1)] = packh2(v, vo);
        } else {
            const int u2 = u - 128, h = u2 >> 5, sidx = u2 & 31;
            const float mu = stat[r][8 + h*2], var = stat[r][9 + h*2];
            float v = (kraw[r][u2] - mu) * rsqrtf(var + 1e-5f) * kls[sidx] + klo[sidx];
            const float vo = __shfl_xor(v, 1);
            if (!(u2 & 1))
                knT4[(((size_t)(u2 >> 3))*N_NODES + i)*4 + ((u2 >> 1) & 3)] = packh2(v, vo);
        }
    }

    if (tid < 64) {
        const int r = tid >> 5, h = (tid >> 3) & 3, ks = tid & 7;
        float uacc = 0.f, tacc = 0.f;
#pragma unroll
        for (int f = ks; f < P3_N; f += 8) {
            float wb = wbS[f*4 + h];
            uacc += qpL[r][f] * wb;
            tacc += kpbL[r][f] * wb;
        }
        float nq = 0.f, nk = 0.f;
#pragma unroll
        for (int f = h*24 + ks*3; f < h*24 + ks*3 + 3; ++f) {
            nq += qpL[r][f]*qpL[r][f];
            nk += kpbL[r][f]*kpbL[r][f];
        }
        uacc += __shfl_xor(uacc,1); uacc += __shfl_xor(uacc,2); uacc += __shfl_xor(uacc,4);
        tacc += __shfl_xor(tacc,1); tacc += __shfl_xor(tacc,2); tacc += __shfl_xor(tacc,4);
        nq   += __shfl_xor(nq,1);   nq   += __shfl_xor(nq,2);   nq   += __shfl_xor(nq,4);
        nk   += __shfl_xor(nk,1);   nk   += __shfl_xor(nk,2);   nk   += __shfl_xor(nk,4);
        if (ks == 0) {
            const int n = i0 + r;
            const float ps = log1pf(expf(gamma[h])) * (1.0f/12.0f);
            iinfo[n*4 + h] = -ps*nq + uacc + b_bias[h];
            jinfo[n*8 + h] = -ps*nk - tacc;
            if (h == 0) {
                jinfo[n*8 + 4] = 10.f * pos[n*15 + 3];
                jinfo[n*8 + 5] = 10.f * pos[n*15 + 4];
                jinfo[n*8 + 6] = 10.f * pos[n*15 + 5];
                jinfo[n*8 + 7] = 0.f;
            }
        }
    }
}

// ---------------------------------------------------------------------------
// Phase 2: TWO query rows per block (ib, ib+1). 1024 threads, grid 256.
// ---------------------------------------------------------------------------
__global__ __launch_bounds__(1024, 4) void attn_kernel(
    const unsigned* __restrict__ qnP, const unsigned* __restrict__ knT4,
    const unsigned* __restrict__ qpP, const unsigned* __restrict__ kpT4,
    const unsigned* __restrict__ BF,
    const unsigned* __restrict__ woPk, const unsigned* __restrict__ wp2,
    const unsigned* __restrict__ remb2,
    const float* __restrict__ jinfo, const float* __restrict__ iinfo,
    const int* __restrict__ resi, const int* __restrict__ chain,
    const int* __restrict__ batch, const void* __restrict__ maskp,
    const float* __restrict__ w_bias, const float* __restrict__ gamma,
    float* __restrict__ out)
{
    const int ib   = blockIdx.x * 2;
    const int tid  = threadIdx.x;
    const int lane = tid & 63;
    const int wv   = tid >> 6;      // 0..15
    const int hp   = tid >> 9;      // 0/1: head pair
    const int j    = tid & 511;

    __shared__ unsigned qpkL[2][64];
    __shared__ unsigned qspkL[2][48];
    __shared__ unsigned wbPk[H_HEADS][8];
    __shared__ __align__(16) unsigned rbfP[2][N_NODES][9];
    __shared__ __align__(16) unsigned attnH2[8][260];       // row = i*4+h
    __shared__ float    mxW[16][4], smW[16][4];
    __shared__ float    asL2[2][H_HEADS];
    __shared__ float    qpiL2[2][P3_N];
    __shared__ float    GLfF2[2][H_HEADS][P3_N];
    __shared__ float    GLfR2[2][H_HEADS][16];
    __shared__ unsigned GLf22[2][H_HEADS][56];
    __shared__ unsigned abktP2[2][H_HEADS][33];
    __shared__ float    resL2[2][HPC];
    __shared__ unsigned resH2[2][FD_N];
    __shared__ float    abktW8[8][2][H_HEADS][66];

    // ---- init ----
    if (tid < 128) {
        const int r = tid >> 6, u = tid & 63;
        qpkL[r][u] = qnP[(size_t)(ib + r)*64 + u];
    } else if (tid < 224) {
        const int v = tid - 128, r = v / 48, f2 = v % 48;
        const int h = f2 / 12;
        const float ps2 = 2.f * log1pf(expf(gamma[h])) * (1.0f/12.0f);
        const unsigned u = qpP[(size_t)(ib + r)*48 + f2];
        qspkL[r][f2] = packh2(ps2*h2lof(u), ps2*h2hif(u));
    } else if (tid < 320) {
        const int v = tid - 224, r = v / 48, f2 = v % 48;
        const unsigned u = qpP[(size_t)(ib + r)*48 + f2];
        qpiL2[r][2*f2]   = h2lof(u);
        qpiL2[r][2*f2+1] = h2hif(u);
    } else if (tid < 352) {
        const int v = tid - 320, h = v >> 3, e = v & 7;
        wbPk[h][e] = packh2(w_bias[(P3_N + 2*e)*H_HEADS + h],
                            w_bias[(P3_N + 2*e + 1)*H_HEADS + h]);
    }
    for (int t = tid; t < 8*2*H_HEADS*66; t += 1024) ((float*)abktW8)[t] = 0.f;

    const int  ri0 = resi[ib], ri1 = resi[ib+1];
    const int  ch0 = chain[ib], ch1 = chain[ib+1];
    const int  ba0 = batch[ib], ba1 = batch[ib+1];
    const bool mi0 = mask_true(maskp, ib), mi1 = mask_true(maskp, ib+1);
    const float dix0 = jinfo[(size_t)ib*8+4], diy0 = jinfo[(size_t)ib*8+5], diz0 = jinfo[(size_t)ib*8+6];
    const float dix1 = jinfo[(size_t)(ib+1)*8+4], diy1 = jinfo[(size_t)(ib+1)*8+5], diz1 = jinfo[(size_t)(ib+1)*8+6];

    const float inv3  = 0.57735026918962576f;
    const float rstep = 0.72727272727272727f;   // 1/1.375

    // ---- per-thread j prework: rbf for row hp; rd/pm for both rows ----
    const float4 vq4 = *(const float4*)(jinfo + (size_t)j*8);
    const float4 dj4 = *(const float4*)(jinfo + (size_t)j*8 + 4);
    const float4 ciA = *(const float4*)(iinfo + (size_t)ib*4);
    const float4 ciB = *(const float4*)(iinfo + (size_t)(ib+1)*4);
    const float vqa[4] = {vq4.x, vq4.y, vq4.z, vq4.w};
    const float cia[2][4] = {{ciA.x, ciA.y, ciA.z, ciA.w},
                             {ciB.x, ciB.y, ciB.z, ciB.w}};
    {
        const float dx = (hp ? dix1 : dix0) - dj4.x;
        const float dy = (hp ? diy1 : diy0) - dj4.y;
        const float dz = (hp ? diz1 : diz0) - dj4.z;
        const float dist = sqrtf(dx*dx + dy*dy + dz*dz + 1e-6f);
#pragma unroll
        for (int p = 0; p < 8; ++p) {
            const float u0 = (dist - (1.375f*(float)(2*p)   + 0.6875f)) * rstep;
            const float u1 = (dist - (1.375f*(float)(2*p+1) + 0.6875f)) * rstep;
            rbfP[hp][j][p] = packh2(__expf(-u0*u0), __expf(-u1*u1));
        }
    }
    const int  rj = resi[j], cj = chain[j], bj = batch[j];
    const bool mj = mask_true(maskp, j);
    bool pmv[2];
    int  rdv[2];
    pmv[0] = mi0 && mj && (ba0 == bj);
    pmv[1] = mi1 && mj && (ba1 == bj);
    rdv[0] = (ch0 != cj) ? 65 : (min(max(ri0 - rj, -32), 32) + 32);
    rdv[1] = (ch1 != cj) ? 65 : (min(max(ri1 - rj, -32), 32) + 32);
    __syncthreads();

    // ================= Pass A: thread=(j,hp), 14 loads -> 4 logits ==========
    float lv[2][2];   // [row][hh], h = hp*2 + hh
    {
        const int h0 = hp*2, h1 = hp*2 + 1;
        const uint4* kcol = (const uint4*)knT4 + j;
        const uint4* pcol = (const uint4*)kpT4 + j;
        const uint4 ka0 = kcol[(size_t)(h0*4 + 0)*N_NODES];
        const uint4 ka1 = kcol[(size_t)(h0*4 + 1)*N_NODES];
        const uint4 ka2 = kcol[(size_t)(h0*4 + 2)*N_NODES];
        const uint4 ka3 = kcol[(size_t)(h0*4 + 3)*N_NODES];
        const uint4 kb0 = kcol[(size_t)(h1*4 + 0)*N_NODES];
        const uint4 kb1 = kcol[(size_t)(h1*4 + 1)*N_NODES];
        const uint4 kb2 = kcol[(size_t)(h1*4 + 2)*N_NODES];
        const uint4 kb3 = kcol[(size_t)(h1*4 + 3)*N_NODES];
        const uint4 pa0 = pcol[(size_t)(h0*3 + 0)*N_NODES];
        const uint4 pa1 = pcol[(size_t)(h0*3 + 1)*N_NODES];
        const uint4 pa2 = pcol[(size_t)(h0*3 + 2)*N_NODES];
        const uint4 pb0 = pcol[(size_t)(h1*3 + 0)*N_NODES];
        const uint4 pb1 = pcol[(size_t)(h1*3 + 1)*N_NODES];
        const uint4 pb2 = pcol[(size_t)(h1*3 + 2)*N_NODES];
        const uint4 rr0a = *(const uint4*)&rbfP[0][j][0];
        const uint4 rr0b = *(const uint4*)&rbfP[0][j][4];
        const uint4 rr1a = *(const uint4*)&rbfP[1][j][0];
        const uint4 rr1b = *(const uint4*)&rbfP[1][j][4];
        const uint4 w0a = *(const uint4*)&wbPk[h0][0];
        const uint4 w0b = *(const uint4*)&wbPk[h0][4];
        const uint4 w1a = *(const uint4*)&wbPk[h1][0];
        const uint4 w1b = *(const uint4*)&wbPk[h1][4];
#pragma unroll
        for (int r = 0; r < 2; ++r) {
            const uint4* qk4 = (const uint4*)&qpkL[r][0];
            const uint4* qs4 = (const uint4*)&qspkL[r][0];
            const uint4 rra = r ? rr1a : rr0a;
            const uint4 rrb = r ? rr1b : rr0b;
            float a0 = 0.f;
            {
                const uint4 q0 = qk4[h0*4 + 0], q1 = qk4[h0*4 + 1];
                const uint4 q2 = qk4[h0*4 + 2], q3 = qk4[h0*4 + 3];
                a0 = dot2u(ka0.x, q0.x, a0); a0 = dot2u(ka0.y, q0.y, a0);
                a0 = dot2u(ka0.z, q0.z, a0); a0 = dot2u(ka0.w, q0.w, a0);
                a0 = dot2u(ka1.x, q1.x, a0); a0 = dot2u(ka1.y, q1.y, a0);
                a0 = dot2u(ka1.z, q1.z, a0); a0 = dot2u(ka1.w, q1.w, a0);
                a0 = dot2u(ka2.x, q2.x, a0); a0 = dot2u(ka2.y, q2.y, a0);
                a0 = dot2u(ka2.z, q2.z, a0); a0 = dot2u(ka2.w, q2.w, a0);
                a0 = dot2u(ka3.x, q3.x, a0); a0 = dot2u(ka3.y, q3.y, a0);
                a0 = dot2u(ka3.z, q3.z, a0); a0 = dot2u(ka3.w, q3.w, a0);
                const uint4 s0 = qs4[h0*3 + 0], s1 = qs4[h0*3 + 1], s2 = qs4[h0*3 + 2];
                a0 = dot2u(pa0.x, s0.x, a0); a0 = dot2u(pa0.y, s0.y, a0);
                a0 = dot2u(pa0.z, s0.z, a0); a0 = dot2u(pa0.w, s0.w, a0);
                a0 = dot2u(pa1.x, s1.x, a0); a0 = dot2u(pa1.y, s1.y, a0);
                a0 = dot2u(pa1.z, s1.z, a0); a0 = dot2u(pa1.w, s1.w, a0);
                a0 = dot2u(pa2.x, s2.x, a0); a0 = dot2u(pa2.y, s2.y, a0);
                a0 = dot2u(pa2.z, s2.z, a0); a0 = dot2u(pa2.w, s2.w, a0);
                a0 = dot2u(rra.x, w0a.x, a0); a0 = dot2u(rra.y, w0a.y, a0);
                a0 = dot2u(rra.z, w0a.z, a0); a0 = dot2u(rra.w, w0a.w, a0);
                a0 = dot2u(rrb.x, w0b.x, a0); a0 = dot2u(rrb.y, w0b.y, a0);
                a0 = dot2u(rrb.z, w0b.z, a0); a0 = dot2u(rrb.w, w0b.w, a0);
            }
            lv[r][0] = pmv[r] ? (a0 + cia[r][h0] + vqa[h0]) * inv3 : -1e9f;
            float a1 = 0.f;
            {
                const uint4 q0 = qk4[h1*4 + 0], q1 = qk4[h1*4 + 1];
                const uint4 q2 = qk4[h1*4 + 2], q3 = qk4[h1*4 + 3];
                a1 = dot2u(kb0.x, q0.x, a1); a1 = dot2u(kb0.y, q0.y, a1);
                a1 = dot2u(kb0.z, q0.z, a1); a1 = dot2u(kb0.w, q0.w, a1);
                a1 = dot2u(kb1.x, q1.x, a1); a1 = dot2u(kb1.y, q1.y, a1);
                a1 = dot2u(kb1.z, q1.z, a1); a1 = dot2u(kb1.w, q1.w, a1);
                a1 = dot2u(kb2.x, q2.x, a1); a1 = dot2u(kb2.y, q2.y, a1);
                a1 = dot2u(kb2.z, q2.z, a1); a1 = dot2u(kb2.w, q2.w, a1);
                a1 = dot2u(kb3.x, q3.x, a1); a1 = dot2u(kb3.y, q3.y, a1);
                a1 = dot2u(kb3.z, q3.z, a1); a1 = dot2u(kb3.w, q3.w, a1);
                const uint4 s0 = qs4[h1*3 + 0], s1 = qs4[h1*3 + 1], s2 = qs4[h1*3 + 2];
                a1 = dot2u(pb0.x, s0.x, a1); a1 = dot2u(pb0.y, s0.y, a1);
                a1 = dot2u(pb0.z, s0.z, a1); a1 = dot2u(pb0.w, s0.w, a1);
                a1 = dot2u(pb1.x, s1.x, a1); a1 = dot2u(pb1.y, s1.y, a1);
                a1 = dot2u(pb1.z, s1.z, a1); a1 = dot2u(pb1.w, s1.w, a1);
                a1 = dot2u(pb2.x, s2.x, a1); a1 = dot2u(pb2.y, s2.y, a1);
                a1 = dot2u(pb2.z, s2.z, a1); a1 = dot2u(pb2.w, s2.w, a1);
                a1 = dot2u(rra.x, w1a.x, a1); a1 = dot2u(rra.y, w1a.y, a1);
                a1 = dot2u(rra.z, w1a.z, a1); a1 = dot2u(rra.w, w1a.w, a1);
                a1 = dot2u(rrb.x, w1b.x, a1); a1 = dot2u(rrb.y, w1b.y, a1);
                a1 = dot2u(rrb.z, w1b.z, a1); a1 = dot2u(rrb.w, w1b.w, a1);
            }
            lv[r][1] = pmv[r] ? (a1 + cia[r][h1] + vqa[h1]) * inv3 : -1e9f;
        }
    }

    // ================= Softmax: intra-wave + 8-wave combine per hp-group ====
    {
        float mx[4] = {lv[0][0], lv[0][1], lv[1][0], lv[1][1]};
#pragma unroll
        for (int off = 1; off < 64; off <<= 1) {
#pragma unroll
            for (int s = 0; s < 4; ++s) mx[s] = fmaxf(mx[s], __shfl_xor(mx[s], off));
        }
        if (lane == 0) *(float4*)&mxW[wv][0] = make_float4(mx[0], mx[1], mx[2], mx[3]);
        __syncthreads();
        float mxg[4] = {-1e30f, -1e30f, -1e30f, -1e30f};
        const int wbase = hp*8;
#pragma unroll
        for (int w = 0; w < 8; ++w) {
            const float4 m = *(const float4*)&mxW[wbase + w][0];
            mxg[0] = fmaxf(mxg[0], m.x); mxg[1] = fmaxf(mxg[1], m.y);
            mxg[2] = fmaxf(mxg[2], m.z); mxg[3] = fmaxf(mxg[3], m.w);
        }
        float e[4], sm[4];
        e[0] = pmv[0] ? __expf(lv[0][0] - mxg[0]) : 0.f;
        e[1] = pmv[0] ? __expf(lv[0][1] - mxg[1]) : 0.f;
        e[2] = pmv[1] ? __expf(lv[1][0] - mxg[2]) : 0.f;
        e[3] = pmv[1] ? __expf(lv[1][1] - mxg[3]) : 0.f;
#pragma unroll
        for (int s = 0; s < 4; ++s) sm[s] = e[s];
#pragma unroll
        for (int off = 1; off < 64; off <<= 1) {
#pragma unroll
            for (int s = 0; s < 4; ++s) sm[s] += __shfl_xor(sm[s], off);
        }
        if (lane == 0) *(float4*)&smW[wv][0] = make_float4(sm[0], sm[1], sm[2], sm[3]);
        __syncthreads();
        float smt[4] = {0.f, 0.f, 0.f, 0.f};
#pragma unroll
        for (int w = 0; w < 8; ++w) {
            const float4 m = *(const float4*)&smW[wbase + w][0];
            smt[0] += m.x; smt[1] += m.y; smt[2] += m.z; smt[3] += m.w;
        }
        float p[4];
#pragma unroll
        for (int s = 0; s < 4; ++s) {
            const float rden = 1.f / fmaxf(smt[s], 1e-37f);
            p[s] = e[s] * rden;
        }
        const int h0 = hp*2;
        atomicAdd(&abktW8[wv & 7][0][h0    ][rdv[0]], p[0]);
        atomicAdd(&abktW8[wv & 7][0][h0 + 1][rdv[0]], p[1]);
        atomicAdd(&abktW8[wv & 7][1][h0    ][rdv[1]], p[2]);
        atomicAdd(&abktW8[wv & 7][1][h0 + 1][rdv[1]], p[3]);
        if (j == 0) {
            asL2[0][h0]     = smt[0] / fmaxf(smt[0], 1e-37f);
            asL2[0][h0 + 1] = smt[1] / fmaxf(smt[1], 1e-37f);
            asL2[1][h0]     = smt[2] / fmaxf(smt[2], 1e-37f);
            asL2[1][h0 + 1] = smt[3] / fmaxf(smt[3], 1e-37f);
        }
#pragma unroll
        for (int s = 0; s < 4; ++s) {
            const float po = __shfl_xor(p[s], 1);
            if (!(j & 1)) {
                const int r = s >> 1, hh = s & 1;
                attnH2[r*4 + h0 + hh][j >> 1] = packh2(p[s], po);
            }
        }
    }
    __syncthreads();

    // ================= Pass B: MFMA P(8 rows) x [val|kp], + rbf waves =======
    if (wv < 14) {
        const int row = lane & 15;
        const int ntA = wv;
        const int ntB = (wv < 6) ? (wv + 14) : -1;
        f32x4 accA = {0.f,0.f,0.f,0.f};
        f32x4 accB = {0.f,0.f,0.f,0.f};
        const uint4* bfp = (const uint4*)BF;
#pragma unroll 4
        for (int kt = 0; kt < 16; ++kt) {
            uint4 au = make_uint4(0u, 0u, 0u, 0u);
            if (row < 8) au = *(const uint4*)&attnH2[row][kt*16 + (lane >> 4)*4];
            const uint4 bA = bfp[(ntA*16 + kt)*64 + lane];
            accA = mfma16(au, bA, accA);
            if (ntB >= 0) {
                const uint4 bB = bfp[(ntB*16 + kt)*64 + lane];
                accB = mfma16(au, bB, accB);
            }
        }
        if (lane < 32) {
            const int r = lane >> 4, c16 = lane & 15;
            {
                const int s = ntA*16 + c16;
                if (s < HPC) {
                    resL2[r][s] = ((const float*)&accA)[s / PAIR_CN];
                } else {
                    const int f = s - HPC;
                    GLfF2[r][0][f] = accA[0];
                    GLfF2[r][1][f] = accA[1];
                    GLfF2[r][2][f] = accA[2];
                    GLfF2[r][3][f] = accA[3];
                }
            }
            if (ntB >= 0) {
                const int s = ntB*16 + c16;
                if (s < HPC) {
                    resL2[r][s] = ((const float*)&accB)[s / PAIR_CN];
                } else {
                    const int f = s - HPC;
                    GLfF2[r][0][f] = accB[0];
                    GLfF2[r][1][f] = accB[1];
                    GLfF2[r][2][f] = accB[2];
                    GLfF2[r][3][f] = accB[3];
                }
            }
        }
    } else {
        // rbf-G: wave 14 -> row 0, wave 15 -> row 1
        const int r = wv - 14;
        const int b = lane >> 2, q = lane & 3;
        const int w = b >> 1;
        const bool hi = (b & 1);
        float a[4] = {0.f, 0.f, 0.f, 0.f};
#pragma unroll 4
        for (int jpp = q*64; jpp < q*64 + 64; ++jpp) {
            const unsigned r0 = rbfP[r][2*jpp][w];
            const unsigned r1 = rbfP[r][2*jpp + 1][w];
            const unsigned ee = hi ? ((r0 >> 16) | (r1 & 0xffff0000u))
                                   : ((r0 & 0xffffu) | (r1 << 16));
            a[0] = dot2u(ee, attnH2[r*4 + 0][jpp], a[0]);
            a[1] = dot2u(ee, attnH2[r*4 + 1][jpp], a[1]);
            a[2] = dot2u(ee, attnH2[r*4 + 2][jpp], a[2]);
            a[3] = dot2u(ee, attnH2[r*4 + 3][jpp], a[3]);
        }
#pragma unroll
        for (int h = 0; h < 4; ++h) {
            a[h] += __shfl_xor(a[h], 1);
            a[h] += __shfl_xor(a[h], 2);
            if (q == 0) GLfR2[r][h][b] = a[h];
        }
    }
    __syncthreads();

    // ================= Combine: GLf2 pack, bucket pack ====================
    for (int t = tid; t < 448; t += 1024) {   // t = r*224 + h*56 + f2
        const int r = t / 224, v = t % 224, h = v / 56, f2 = v % 56;
        if (f2 < 48) {
            GLf22[r][h][f2] = packh2(qpiL2[r][2*f2]*asL2[r][h]     - GLfF2[r][h][2*f2],
                                     qpiL2[r][2*f2 + 1]*asL2[r][h] - GLfF2[r][h][2*f2 + 1]);
        } else {
            GLf22[r][h][f2] = packh2(GLfR2[r][h][(f2 - 48)*2], GLfR2[r][h][(f2 - 48)*2 + 1]);
        }
    }
    for (int t = tid; t < 264; t += 1024) {   // t = r*132 + h*33 + r2
        const int r = t / 132, v = t % 132, h = v / 33, r2 = v % 33;
        float s0 = 0.f, s1 = 0.f;
#pragma unroll
        for (int w = 0; w < 8; ++w) {
            s0 += abktW8[w][r][h][2*r2];
            s1 += abktW8[w][r][h][2*r2 + 1];
        }
        abktP2[r][h][r2] = packh2(s0, s1);
    }
    __syncthreads();

    // ================= Epilogue: weights loaded once, 2 rows ================
    if (tid < HPC) {
        const int h = tid / PAIR_CN, c = tid - h*PAIR_CN;
        float r0 = resL2[0][tid];
        float r1 = resL2[1][tid];
        {
            unsigned buf[16];
#pragma unroll
            for (int t = 0; t < 16; ++t) buf[t] = remb2[t*56 + c];
#pragma unroll
            for (int t = 0; t < 16; ++t) {
                r0 = dot2u(buf[t], abktP2[0][h][t], r0);
                r1 = dot2u(buf[t], abktP2[1][h][t], r1);
            }
#pragma unroll
            for (int t = 0; t < 16; ++t) buf[t] = remb2[(16 + t)*56 + c];
#pragma unroll
            for (int t = 0; t < 16; ++t) {
                r0 = dot2u(buf[t], abktP2[0][h][16 + t], r0);
                r1 = dot2u(buf[t], abktP2[1][h][16 + t], r1);
            }
            const unsigned b32 = remb2[32*56 + c];
            r0 = dot2u(b32, abktP2[0][h][32], r0);
            r1 = dot2u(b32, abktP2[1][h][32], r1);
        }
        {
            unsigned buf[14];
#pragma unroll
            for (int qq = 0; qq < 4; ++qq) {
#pragma unroll
                for (int t = 0; t < 14; ++t) buf[t] = wp2[(qq*14 + t)*56 + c];
#pragma unroll
                for (int t = 0; t < 14; ++t) {
                    r0 = dot2u(buf[t], GLf22[0][h][qq*14 + t], r0);
                    r1 = dot2u(buf[t], GLf22[1][h][qq*14 + t], r1);
                }
            }
        }
        resL2[0][tid] = r0;
        resL2[1][tid] = r1;
    }
    __syncthreads();

    if (tid < 2*FD_N) {
        const int r = tid / FD_N, t2 = tid % FD_N;
        resH2[r][t2] = packh2(resL2[r][2*t2], resL2[r][2*t2 + 1]);
    }
    __syncthreads();

    // ================= out: woPk loaded once, 2 rows =======================
    if (tid < 512) {
        const int col = tid >> 1, ph = tid & 1;
        float o0 = 0.f, o1 = 0.f;
        unsigned buf[14];
#pragma unroll
        for (int qq = 0; qq < 4; ++qq) {
            const int base = ph*56 + qq*14;
#pragma unroll
            for (int t = 0; t < 14; ++t) buf[t] = woPk[(base + t)*256 + col];
#pragma unroll
            for (int t = 0; t < 14; ++t) {
                o0 = dot2u(buf[t], resH2[0][base + t], o0);
                o1 = dot2u(buf[t], resH2[1][base + t], o1);
            }
        }
        o0 += __shfl_xor(o0, 1);
        o1 += __shfl_xor(o1, 1);
        if (ph == 0) {
            out[(size_t)ib*DIM + col]       = o0;
            out[(size_t)(ib + 1)*DIM + col] = o1;
        }
    }
}

// ---------------------------------------------------------------------------
extern "C" void kernel_launch(void* const* d_in, const int* in_sizes, int n_in,
                              void* d_out, int out_size, void* d_ws, size_t ws_size,
                              hipStream_t stream) {
    (void)in_sizes; (void)n_in; (void)out_size; (void)ws_size;
    const float* local = (const float*)d_in[0];
    const float* pos   = (const float*)d_in[1];
    const int*   resi  = (const int*)d_in[2];
    const int*   chain = (const int*)d_in[3];
    const int*   batch = (const int*)d_in[4];
    const void*  maskp = d_in[5];
    const float* qls   = (const float*)d_in[6];
    const float* qlo   = (const float*)d_in[7];
    const float* kls   = (const float*)d_in[8];
    const float* klo   = (const float*)d_in[9];
    const float* w_q   = (const float*)d_in[10];
    const float* b_q   = (const float*)d_in[11];
    const float* w_k   = (const float*)d_in[12];
    const float* b_k   = (const float*)d_in[13];
    const float* w_v   = (const float*)d_in[14];
    const float* b_v   = (const float*)d_in[15];
    const float* w_qp  = (const float*)d_in[16];
    const float* b_qp  = (const float*)d_in[17];
    const float* w_kp  = (const float*)d_in[18];
    const float* b_kp  = (const float*)d_in[19];
    const float* w_vp  = (const float*)d_in[20];
    const float* b_vp  = (const float*)d_in[21];
    const float* remb  = (const float*)d_in[22];
    const float* w_pair= (const float*)d_in[23];
    const float* w_bias= (const float*)d_in[24];
    const float* b_bias= (const float*)d_in[25];
    const float* gamma = (const float*)d_in[26];
    const float* w_out = (const float*)d_in[27];

    char* ws = (char*)d_ws;
    unsigned* qnP   = (unsigned*)(ws);            // 131072 B [512][64]
    unsigned* qpP   = (unsigned*)(ws + 131072);   //  98304 B [512][48]
    unsigned* knT4  = (unsigned*)(ws + 229376);   // 131072 B [16][512][4]
    unsigned* kpT4  = (unsigned*)(ws + 360448);   //  98304 B [12][512][4]
    unsigned* BF    = (unsigned*)(ws + 458752);   // 327680 B [20][16][64][4]
    float*    jinf  = (float*)(ws + 786432);      //  16384 B
    float*    iinf  = (float*)(ws + 802816);      //   8192 B
    unsigned* woPk  = (unsigned*)(ws + 811008);   // 114688 B [112][256]
    unsigned* wp2   = (unsigned*)(ws + 925696);   //  12544 B [56][56]
    unsigned* remb2 = (unsigned*)(ws + 938240);   //   7392 B [33][56]

    proj_kernel<<<N_NODES / 2, 512, 0, stream>>>(
        local, pos, qls, qlo, kls, klo,
        w_q, b_q, w_k, b_k, w_v, b_v,
        w_qp, b_qp, w_kp, b_kp, w_vp, b_vp,
        w_bias, b_bias, gamma,
        remb, w_pair, w_out,
        qnP, knT4, qpP, kpT4, BF,
        woPk, wp2, remb2, jinf, iinf);

    attn_kernel<<<N_NODES / 2, 1024, 0, stream>>>(
        qnP, knT4, qpP, kpT4, BF,
        woPk, wp2, remb2, jinf, iinf,
        resi, chain, batch, maskp,
        w_bias, gamma,
        (float*)d_out);
}

// Round 20
// 53.030 us; speedup vs baseline: 3.7984x; 1.0143x over previous
//
#include <hip/hip_runtime.h>
#include <hip/hip_bf16.h>
#include <cstddef>

// Problem constants (N, D, S, H, QP, VP) = (512, 256, 32, 4, 8, 8)
#define N_NODES 512
#define DIM     256
#define H_HEADS 4
#define PAIR_CN 56    // S + 3*VP
#define P3_N    96    // H*QP*3
#define FD_N    112   // P3 + 16
#define HPC     224   // H * PAIR_C

typedef _Float16 h2v  __attribute__((ext_vector_type(2)));
typedef _Float16 f16x8 __attribute__((ext_vector_type(8)));
typedef float    f32x4 __attribute__((ext_vector_type(4)));

__device__ __forceinline__ bool mask_true(const void* m, int idx) {
    if (((const unsigned char*)m)[idx] != 0) return true;
    return ((const int*)m)[idx] != 0;
}
__device__ __forceinline__ unsigned packh2(float a, float b) {
    _Float16 ha = (_Float16)a, hb = (_Float16)b;
    unsigned short ua, ub;
    __builtin_memcpy(&ua, &ha, 2); __builtin_memcpy(&ub, &hb, 2);
    return (unsigned)ua | ((unsigned)ub << 16);
}
__device__ __forceinline__ float h2lof(unsigned u) {
    unsigned short t = (unsigned short)(u & 0xffff);
    _Float16 h; __builtin_memcpy(&h, &t, 2); return (float)h;
}
__device__ __forceinline__ float h2hif(unsigned u) {
    unsigned short t = (unsigned short)(u >> 16);
    _Float16 h; __builtin_memcpy(&h, &t, 2); return (float)h;
}
__device__ __forceinline__ float dot2u(unsigned a, unsigned b, float c) {
#if __has_builtin(__builtin_amdgcn_fdot2)
    h2v ha, hb;
    __builtin_memcpy(&ha, &a, 4);
    __builtin_memcpy(&hb, &b, 4);
    return __builtin_amdgcn_fdot2(ha, hb, c, false);
#else
    return c + h2lof(a)*h2lof(b) + h2hif(a)*h2hif(b);
#endif
}
__device__ __forceinline__ f32x4 mfma16(uint4 a, uint4 b, f32x4 c) {
    f16x8 af, bf;
    __builtin_memcpy(&af, &a, 16);
    __builtin_memcpy(&bf, &b, 16);
    return __builtin_amdgcn_mfma_f32_16x16x32_f16(af, bf, c, 0, 0, 0);
}

// ---------------------------------------------------------------------------
// Phase 1: projections + LayerNorm + separable terms + weight packing.
// Weight packing spread over ALL 256 blocks (1 element/thread, no tail skew).
// ---------------------------------------------------------------------------
__global__ __launch_bounds__(512) void proj_kernel(
    const float* __restrict__ local, const float* __restrict__ pos,
    const float* __restrict__ qls, const float* __restrict__ qlo,
    const float* __restrict__ kls, const float* __restrict__ klo,
    const float* __restrict__ w_q, const float* __restrict__ b_q,
    const float* __restrict__ w_k, const float* __restrict__ b_k,
    const float* __restrict__ w_v, const float* __restrict__ b_v,
    const float* __restrict__ w_qp, const float* __restrict__ b_qp,
    const float* __restrict__ w_kp, const float* __restrict__ b_kp,
    const float* __restrict__ w_vp, const float* __restrict__ b_vp,
    const float* __restrict__ w_bias, const float* __restrict__ b_bias,
    const float* __restrict__ gamma,
    const float* __restrict__ remb, const float* __restrict__ w_pair,
    const float* __restrict__ w_out,
    unsigned* __restrict__ qnP, unsigned* __restrict__ knT4,
    unsigned* __restrict__ qpP, unsigned* __restrict__ kpT4,
    unsigned* __restrict__ BF,
    unsigned* __restrict__ woPk, unsigned* __restrict__ wp2,
    unsigned* __restrict__ remb2,
    float* __restrict__ jinfo, float* __restrict__ iinfo)
{
    const int i0 = blockIdx.x * 2;
    const int tid = threadIdx.x;

    __shared__ float xL[2][DIM];
    __shared__ float qraw[2][128];
    __shared__ float kraw[2][128];
    __shared__ float stat[2][16];
    __shared__ float qpL[2][P3_N];
    __shared__ float kpbL[2][P3_N];
    __shared__ float wbS[384];

    // ---- weight packing: 1 element per thread across the whole grid ----
    {
        const int t = blockIdx.x * 512 + tid;   // 0..131071 >= 33656
        if (t < 28672) {
            const int t2 = t >> 8, colx = t & 255;
            woPk[t] = packh2(w_out[(size_t)(2*t2)*DIM + colx],
                             w_out[(size_t)(2*t2 + 1)*DIM + colx]);
        } else if (t < 31808) {
            const int v = t - 28672, f2 = v / 56, cx = v % 56;
            wp2[v] = packh2(w_pair[(2*f2)*PAIR_CN + cx],
                            w_pair[(2*f2 + 1)*PAIR_CN + cx]);
        } else if (t < 33656) {
            const int v = t - 31808, r2 = v / 56, cx = v % 56;
            remb2[v] = packh2(remb[(2*r2)*PAIR_CN + cx],
                              remb[(2*r2 + 1)*PAIR_CN + cx]);
        }
    }

    {
        const int r = tid >> 8, d = tid & 255;
        xL[r][d] = local[(size_t)(i0 + r) * DIM + d];
    }
    if (tid < 384) wbS[tid] = w_bias[tid];
    __syncthreads();

    const int cstBF = ((i0 >> 5) << 8) + (((i0 >> 3) & 3) << 6) + ((i0 >> 1) & 3);

    if (tid < 336) {
        const int colg = tid >> 1, dh = tid & 1;
        const int col = colg * 4;
        const float* w; int width, c, seg;
        if      (col < 128) { w = w_q;  c = col;       width = 128; seg = 0; }
        else if (col < 256) { w = w_k;  c = col - 128; width = 128; seg = 1; }
        else if (col < 384) { w = w_v;  c = col - 256; width = 128; seg = 2; }
        else if (col < 480) { w = w_qp; c = col - 384; width = 96;  seg = 3; }
        else if (col < 576) { w = w_kp; c = col - 480; width = 96;  seg = 4; }
        else                { w = w_vp; c = col - 576; width = 96;  seg = 5; }

        float acc[2][4] = {{0.f,0.f,0.f,0.f},{0.f,0.f,0.f,0.f}};
        const float* wc = w + c;
        const int dbase = dh * 128;
#pragma unroll 1
        for (int bb = 0; bb < 16; ++bb) {
            const int d0 = dbase + bb*8;
            const float4 wv0 = *(const float4*)(wc + (size_t)(d0 + 0)*width);
            const float4 wv1 = *(const float4*)(wc + (size_t)(d0 + 1)*width);
            const float4 wv2 = *(const float4*)(wc + (size_t)(d0 + 2)*width);
            const float4 wv3 = *(const float4*)(wc + (size_t)(d0 + 3)*width);
            const float4 wv4 = *(const float4*)(wc + (size_t)(d0 + 4)*width);
            const float4 wv5 = *(const float4*)(wc + (size_t)(d0 + 5)*width);
            const float4 wv6 = *(const float4*)(wc + (size_t)(d0 + 6)*width);
            const float4 wv7 = *(const float4*)(wc + (size_t)(d0 + 7)*width);
#pragma unroll
            for (int r = 0; r < 2; ++r) {
                const float x0 = xL[r][d0 + 0], x1 = xL[r][d0 + 1];
                const float x2 = xL[r][d0 + 2], x3 = xL[r][d0 + 3];
                const float x4 = xL[r][d0 + 4], x5 = xL[r][d0 + 5];
                const float x6 = xL[r][d0 + 6], x7 = xL[r][d0 + 7];
                acc[r][0] += x0*wv0.x + x1*wv1.x + x2*wv2.x + x3*wv3.x
                           + x4*wv4.x + x5*wv5.x + x6*wv6.x + x7*wv7.x;
                acc[r][1] += x0*wv0.y + x1*wv1.y + x2*wv2.y + x3*wv3.y
                           + x4*wv4.y + x5*wv5.y + x6*wv6.y + x7*wv7.y;
                acc[r][2] += x0*wv0.z + x1*wv1.z + x2*wv2.z + x3*wv3.z
                           + x4*wv4.z + x5*wv5.z + x6*wv6.z + x7*wv7.z;
                acc[r][3] += x0*wv0.w + x1*wv1.w + x2*wv2.w + x3*wv3.w
                           + x4*wv4.w + x5*wv5.w + x6*wv6.w + x7*wv7.w;
            }
        }
#pragma unroll
        for (int r = 0; r < 2; ++r)
#pragma unroll
            for (int e = 0; e < 4; ++e)
                acc[r][e] += __shfl_xor(acc[r][e], 1);

        if (dh == 0) {
            const float cax0 = pos[i0*15+3],     cay0 = pos[i0*15+4],     caz0 = pos[i0*15+5];
            const float cax1 = pos[(i0+1)*15+3], cay1 = pos[(i0+1)*15+4], caz1 = pos[(i0+1)*15+5];
            float fr0[4], fr1[4];
            const bool isKp = (seg == 4), isQp = (seg == 3);
#pragma unroll
            for (int e = 0; e < 4; ++e) {
                const int cc = c + e;
                const float v0 = acc[0][e], v1 = acc[1][e];
                if (seg == 0) {
                    qraw[0][cc] = v0 + b_q[cc];
                    qraw[1][cc] = v1 + b_q[cc];
                } else if (seg == 1) {
                    kraw[0][cc] = v0 + b_k[cc];
                    kraw[1][cc] = v1 + b_k[cc];
                } else if (seg == 2) {
                    const int h = cc >> 5, sc = cc & 31;
                    const int colF = h*PAIR_CN + sc;
                    BF[(colF >> 4)*4096 + (colF & 15)*4 + cstBF] =
                        packh2(v0 + b_v[cc], v1 + b_v[cc]);
                } else if (seg == 3) {
                    const int x = cc % 3;
                    const float cav0 = (x==0)?cax0:((x==1)?cay0:caz0);
                    const float cav1 = (x==0)?cax1:((x==1)?cay1:caz1);
                    const float r0 = v0 + b_qp[cc] + cav0;
                    const float r1 = v1 + b_qp[cc] + cav1;
                    fr0[e] = r0; fr1[e] = r1;
                    qpL[0][cc] = r0; qpL[1][cc] = r1;
                } else if (seg == 4) {
                    const int x = cc % 3;
                    const float cav0 = (x==0)?cax0:((x==1)?cay0:caz0);
                    const float cav1 = (x==0)?cax1:((x==1)?cay1:caz1);
                    const float r0 = v0 + b_kp[cc] + cav0;
                    const float r1 = v1 + b_kp[cc] + cav1;
                    fr0[e] = r0; fr1[e] = r1;
                    const int colF = 224 + cc;
                    BF[(colF >> 4)*4096 + (colF & 15)*4 + cstBF] = packh2(r0, r1);
                    kpbL[0][cc] = (float)(_Float16)r0;
                    kpbL[1][cc] = (float)(_Float16)r1;
                } else {
                    const int h = cc / 24, rr = cc % 24, x = cc % 3;
                    const float cav0 = (x==0)?cax0:((x==1)?cay0:caz0);
                    const float cav1 = (x==0)?cax1:((x==1)?cay1:caz1);
                    const int colF = h*PAIR_CN + 32 + rr;
                    BF[(colF >> 4)*4096 + (colF & 15)*4 + cstBF] =
                        packh2(v0 + b_vp[cc] + cav0, v1 + b_vp[cc] + cav1);
                }
            }
            if (isQp) {
                const int f2 = c >> 1;
                qpP[(size_t)i0*48 + f2]         = packh2(fr0[0], fr0[1]);
                qpP[(size_t)i0*48 + f2 + 1]     = packh2(fr0[2], fr0[3]);
                qpP[(size_t)(i0+1)*48 + f2]     = packh2(fr1[0], fr1[1]);
                qpP[(size_t)(i0+1)*48 + f2 + 1] = packh2(fr1[2], fr1[3]);
            }
            if (isKp) {
                const int f2 = c >> 1;
                const int fq = f2 >> 2;
                kpT4[((size_t)fq*N_NODES + i0    )*4 + (f2 & 3)]       = packh2(fr0[0], fr0[1]);
                kpT4[((size_t)fq*N_NODES + i0    )*4 + ((f2 + 1) & 3)] = packh2(fr0[2], fr0[3]);
                kpT4[((size_t)fq*N_NODES + i0 + 1)*4 + (f2 & 3)]       = packh2(fr1[0], fr1[1]);
                kpT4[((size_t)fq*N_NODES + i0 + 1)*4 + ((f2 + 1) & 3)] = packh2(fr1[2], fr1[3]);
            }
        }
    }
    __syncthreads();

    if (tid < 16) {
        const int r = tid >> 3, t = tid & 7;
        const float* src = (t < 4) ? qraw[r] : kraw[r];
        const int h = t & 3, base = (t < 4) ? 0 : 8;
        float mu = 0.f;
        for (int c = 0; c < 32; ++c) mu += src[h*32 + c];
        mu *= (1.f/32.f);
        float var = 0.f;
        for (int c = 0; c < 32; ++c) { float d = src[h*32 + c] - mu; var += d*d; }
        var *= (1.f/32.f);
        stat[r][base + h*2 + 0] = mu;
        stat[r][base + h*2 + 1] = var;
    }
    __syncthreads();

    {
        const int r = tid >> 8, u = tid & 255;
        const int i = i0 + r;
        if (u < 128) {
            const int h = u >> 5, sidx = u & 31;
            const float mu = stat[r][h*2], var = stat[r][h*2+1];
            float v = (qraw[r][u] - mu) * rsqrtf(var + 1e-5f) * qls[sidx] + qlo[sidx];
            v *= 0.17677669529663687f;  // * sqrt(1/S)
            const float vo = __shfl_xor(v, 1);
            if (!(u & 1)) qnP[(size_t)i*64 + (u >> 1)] = packh2(v, vo);
        } else {
            const int u2 = u - 128, h = u2 >> 5, sidx = u2 & 31;
            const float mu = stat[r][8 + h*2], var = stat[r][9 + h*2];
            float v = (kraw[r][u2] - mu) * rsqrtf(var + 1e-5f) * kls[sidx] + klo[sidx];
            const float vo = __shfl_xor(v, 1);
            if (!(u2 & 1))
                knT4[(((size_t)(u2 >> 3))*N_NODES + i)*4 + ((u2 >> 1) & 3)] = packh2(v, vo);
        }
    }

    if (tid < 64) {
        const int r = tid >> 5, h = (tid >> 3) & 3, ks = tid & 7;
        float uacc = 0.f, tacc = 0.f;
#pragma unroll
        for (int f = ks; f < P3_N; f += 8) {
            float wb = wbS[f*4 + h];
            uacc += qpL[r][f] * wb;
            tacc += kpbL[r][f] * wb;
        }
        float nq = 0.f, nk = 0.f;
#pragma unroll
        for (int f = h*24 + ks*3; f < h*24 + ks*3 + 3; ++f) {
            nq += qpL[r][f]*qpL[r][f];
            nk += kpbL[r][f]*kpbL[r][f];
        }
        uacc += __shfl_xor(uacc,1); uacc += __shfl_xor(uacc,2); uacc += __shfl_xor(uacc,4);
        tacc += __shfl_xor(tacc,1); tacc += __shfl_xor(tacc,2); tacc += __shfl_xor(tacc,4);
        nq   += __shfl_xor(nq,1);   nq   += __shfl_xor(nq,2);   nq   += __shfl_xor(nq,4);
        nk   += __shfl_xor(nk,1);   nk   += __shfl_xor(nk,2);   nk   += __shfl_xor(nk,4);
        if (ks == 0) {
            const int n = i0 + r;
            const float ps = log1pf(expf(gamma[h])) * (1.0f/12.0f);
            iinfo[n*4 + h] = -ps*nq + uacc + b_bias[h];
            jinfo[n*8 + h] = -ps*nk - tacc;
            if (h == 0) {
                jinfo[n*8 + 4] = 10.f * pos[n*15 + 3];
                jinfo[n*8 + 5] = 10.f * pos[n*15 + 4];
                jinfo[n*8 + 6] = 10.f * pos[n*15 + 5];
                jinfo[n*8 + 7] = 0.f;
            }
        }
    }
}

// ---------------------------------------------------------------------------
// Phase 2: TWO query rows per block (ib, ib+1). 1024 threads, grid 256.
// (unchanged from round 19)
// ---------------------------------------------------------------------------
__global__ __launch_bounds__(1024, 4) void attn_kernel(
    const unsigned* __restrict__ qnP, const unsigned* __restrict__ knT4,
    const unsigned* __restrict__ qpP, const unsigned* __restrict__ kpT4,
    const unsigned* __restrict__ BF,
    const unsigned* __restrict__ woPk, const unsigned* __restrict__ wp2,
    const unsigned* __restrict__ remb2,
    const float* __restrict__ jinfo, const float* __restrict__ iinfo,
    const int* __restrict__ resi, const int* __restrict__ chain,
    const int* __restrict__ batch, const void* __restrict__ maskp,
    const float* __restrict__ w_bias, const float* __restrict__ gamma,
    float* __restrict__ out)
{
    const int ib   = blockIdx.x * 2;
    const int tid  = threadIdx.x;
    const int lane = tid & 63;
    const int wv   = tid >> 6;      // 0..15
    const int hp   = tid >> 9;      // 0/1: head pair
    const int j    = tid & 511;

    __shared__ unsigned qpkL[2][64];
    __shared__ unsigned qspkL[2][48];
    __shared__ unsigned wbPk[H_HEADS][8];
    __shared__ __align__(16) unsigned rbfP[2][N_NODES][9];
    __shared__ __align__(16) unsigned attnH2[8][260];       // row = i*4+h
    __shared__ float    mxW[16][4], smW[16][4];
    __shared__ float    asL2[2][H_HEADS];
    __shared__ float    qpiL2[2][P3_N];
    __shared__ float    GLfF2[2][H_HEADS][P3_N];
    __shared__ float    GLfR2[2][H_HEADS][16];
    __shared__ unsigned GLf22[2][H_HEADS][56];
    __shared__ unsigned abktP2[2][H_HEADS][33];
    __shared__ float    resL2[2][HPC];
    __shared__ unsigned resH2[2][FD_N];
    __shared__ float    abktW8[8][2][H_HEADS][66];

    // ---- init ----
    if (tid < 128) {
        const int r = tid >> 6, u = tid & 63;
        qpkL[r][u] = qnP[(size_t)(ib + r)*64 + u];
    } else if (tid < 224) {
        const int v = tid - 128, r = v / 48, f2 = v % 48;
        const int h = f2 / 12;
        const float ps2 = 2.f * log1pf(expf(gamma[h])) * (1.0f/12.0f);
        const unsigned u = qpP[(size_t)(ib + r)*48 + f2];
        qspkL[r][f2] = packh2(ps2*h2lof(u), ps2*h2hif(u));
    } else if (tid < 320) {
        const int v = tid - 224, r = v / 48, f2 = v % 48;
        const unsigned u = qpP[(size_t)(ib + r)*48 + f2];
        qpiL2[r][2*f2]   = h2lof(u);
        qpiL2[r][2*f2+1] = h2hif(u);
    } else if (tid < 352) {
        const int v = tid - 320, h = v >> 3, e = v & 7;
        wbPk[h][e] = packh2(w_bias[(P3_N + 2*e)*H_HEADS + h],
                            w_bias[(P3_N + 2*e + 1)*H_HEADS + h]);
    }
    for (int t = tid; t < 8*2*H_HEADS*66; t += 1024) ((float*)abktW8)[t] = 0.f;

    const int  ri0 = resi[ib], ri1 = resi[ib+1];
    const int  ch0 = chain[ib], ch1 = chain[ib+1];
    const int  ba0 = batch[ib], ba1 = batch[ib+1];
    const bool mi0 = mask_true(maskp, ib), mi1 = mask_true(maskp, ib+1);
    const float dix0 = jinfo[(size_t)ib*8+4], diy0 = jinfo[(size_t)ib*8+5], diz0 = jinfo[(size_t)ib*8+6];
    const float dix1 = jinfo[(size_t)(ib+1)*8+4], diy1 = jinfo[(size_t)(ib+1)*8+5], diz1 = jinfo[(size_t)(ib+1)*8+6];

    const float inv3  = 0.57735026918962576f;
    const float rstep = 0.72727272727272727f;   // 1/1.375

    // ---- per-thread j prework: rbf for row hp; rd/pm for both rows ----
    const float4 vq4 = *(const float4*)(jinfo + (size_t)j*8);
    const float4 dj4 = *(const float4*)(jinfo + (size_t)j*8 + 4);
    const float4 ciA = *(const float4*)(iinfo + (size_t)ib*4);
    const float4 ciB = *(const float4*)(iinfo + (size_t)(ib+1)*4);
    const float vqa[4] = {vq4.x, vq4.y, vq4.z, vq4.w};
    const float cia[2][4] = {{ciA.x, ciA.y, ciA.z, ciA.w},
                             {ciB.x, ciB.y, ciB.z, ciB.w}};
    {
        const float dx = (hp ? dix1 : dix0) - dj4.x;
        const float dy = (hp ? diy1 : diy0) - dj4.y;
        const float dz = (hp ? diz1 : diz0) - dj4.z;
        const float dist = sqrtf(dx*dx + dy*dy + dz*dz + 1e-6f);
#pragma unroll
        for (int p = 0; p < 8; ++p) {
            const float u0 = (dist - (1.375f*(float)(2*p)   + 0.6875f)) * rstep;
            const float u1 = (dist - (1.375f*(float)(2*p+1) + 0.6875f)) * rstep;
            rbfP[hp][j][p] = packh2(__expf(-u0*u0), __expf(-u1*u1));
        }
    }
    const int  rj = resi[j], cj = chain[j], bj = batch[j];
    const bool mj = mask_true(maskp, j);
    bool pmv[2];
    int  rdv[2];
    pmv[0] = mi0 && mj && (ba0 == bj);
    pmv[1] = mi1 && mj && (ba1 == bj);
    rdv[0] = (ch0 != cj) ? 65 : (min(max(ri0 - rj, -32), 32) + 32);
    rdv[1] = (ch1 != cj) ? 65 : (min(max(ri1 - rj, -32), 32) + 32);
    __syncthreads();

    // ================= Pass A: thread=(j,hp), 14 loads -> 4 logits ==========
    float lv[2][2];   // [row][hh], h = hp*2 + hh
    {
        const int h0 = hp*2, h1 = hp*2 + 1;
        const uint4* kcol = (const uint4*)knT4 + j;
        const uint4* pcol = (const uint4*)kpT4 + j;
        const uint4 ka0 = kcol[(size_t)(h0*4 + 0)*N_NODES];
        const uint4 ka1 = kcol[(size_t)(h0*4 + 1)*N_NODES];
        const uint4 ka2 = kcol[(size_t)(h0*4 + 2)*N_NODES];
        const uint4 ka3 = kcol[(size_t)(h0*4 + 3)*N_NODES];
        const uint4 kb0 = kcol[(size_t)(h1*4 + 0)*N_NODES];
        const uint4 kb1 = kcol[(size_t)(h1*4 + 1)*N_NODES];
        const uint4 kb2 = kcol[(size_t)(h1*4 + 2)*N_NODES];
        const uint4 kb3 = kcol[(size_t)(h1*4 + 3)*N_NODES];
        const uint4 pa0 = pcol[(size_t)(h0*3 + 0)*N_NODES];
        const uint4 pa1 = pcol[(size_t)(h0*3 + 1)*N_NODES];
        const uint4 pa2 = pcol[(size_t)(h0*3 + 2)*N_NODES];
        const uint4 pb0 = pcol[(size_t)(h1*3 + 0)*N_NODES];
        const uint4 pb1 = pcol[(size_t)(h1*3 + 1)*N_NODES];
        const uint4 pb2 = pcol[(size_t)(h1*3 + 2)*N_NODES];
        const uint4 rr0a = *(const uint4*)&rbfP[0][j][0];
        const uint4 rr0b = *(const uint4*)&rbfP[0][j][4];
        const uint4 rr1a = *(const uint4*)&rbfP[1][j][0];
        const uint4 rr1b = *(const uint4*)&rbfP[1][j][4];
        const uint4 w0a = *(const uint4*)&wbPk[h0][0];
        const uint4 w0b = *(const uint4*)&wbPk[h0][4];
        const uint4 w1a = *(const uint4*)&wbPk[h1][0];
        const uint4 w1b = *(const uint4*)&wbPk[h1][4];
#pragma unroll
        for (int r = 0; r < 2; ++r) {
            const uint4* qk4 = (const uint4*)&qpkL[r][0];
            const uint4* qs4 = (const uint4*)&qspkL[r][0];
            const uint4 rra = r ? rr1a : rr0a;
            const uint4 rrb = r ? rr1b : rr0b;
            float a0 = 0.f;
            {
                const uint4 q0 = qk4[h0*4 + 0], q1 = qk4[h0*4 + 1];
                const uint4 q2 = qk4[h0*4 + 2], q3 = qk4[h0*4 + 3];
                a0 = dot2u(ka0.x, q0.x, a0); a0 = dot2u(ka0.y, q0.y, a0);
                a0 = dot2u(ka0.z, q0.z, a0); a0 = dot2u(ka0.w, q0.w, a0);
                a0 = dot2u(ka1.x, q1.x, a0); a0 = dot2u(ka1.y, q1.y, a0);
                a0 = dot2u(ka1.z, q1.z, a0); a0 = dot2u(ka1.w, q1.w, a0);
                a0 = dot2u(ka2.x, q2.x, a0); a0 = dot2u(ka2.y, q2.y, a0);
                a0 = dot2u(ka2.z, q2.z, a0); a0 = dot2u(ka2.w, q2.w, a0);
                a0 = dot2u(ka3.x, q3.x, a0); a0 = dot2u(ka3.y, q3.y, a0);
                a0 = dot2u(ka3.z, q3.z, a0); a0 = dot2u(ka3.w, q3.w, a0);
                const uint4 s0 = qs4[h0*3 + 0], s1 = qs4[h0*3 + 1], s2 = qs4[h0*3 + 2];
                a0 = dot2u(pa0.x, s0.x, a0); a0 = dot2u(pa0.y, s0.y, a0);
                a0 = dot2u(pa0.z, s0.z, a0); a0 = dot2u(pa0.w, s0.w, a0);
                a0 = dot2u(pa1.x, s1.x, a0); a0 = dot2u(pa1.y, s1.y, a0);
                a0 = dot2u(pa1.z, s1.z, a0); a0 = dot2u(pa1.w, s1.w, a0);
                a0 = dot2u(pa2.x, s2.x, a0); a0 = dot2u(pa2.y, s2.y, a0);
                a0 = dot2u(pa2.z, s2.z, a0); a0 = dot2u(pa2.w, s2.w, a0);
                a0 = dot2u(rra.x, w0a.x, a0); a0 = dot2u(rra.y, w0a.y, a0);
                a0 = dot2u(rra.z, w0a.z, a0); a0 = dot2u(rra.w, w0a.w, a0);
                a0 = dot2u(rrb.x, w0b.x, a0); a0 = dot2u(rrb.y, w0b.y, a0);
                a0 = dot2u(rrb.z, w0b.z, a0); a0 = dot2u(rrb.w, w0b.w, a0);
            }
            lv[r][0] = pmv[r] ? (a0 + cia[r][h0] + vqa[h0]) * inv3 : -1e9f;
            float a1 = 0.f;
            {
                const uint4 q0 = qk4[h1*4 + 0], q1 = qk4[h1*4 + 1];
                const uint4 q2 = qk4[h1*4 + 2], q3 = qk4[h1*4 + 3];
                a1 = dot2u(kb0.x, q0.x, a1); a1 = dot2u(kb0.y, q0.y, a1);
                a1 = dot2u(kb0.z, q0.z, a1); a1 = dot2u(kb0.w, q0.w, a1);
                a1 = dot2u(kb1.x, q1.x, a1); a1 = dot2u(kb1.y, q1.y, a1);
                a1 = dot2u(kb1.z, q1.z, a1); a1 = dot2u(kb1.w, q1.w, a1);
                a1 = dot2u(kb2.x, q2.x, a1); a1 = dot2u(kb2.y, q2.y, a1);
                a1 = dot2u(kb2.z, q2.z, a1); a1 = dot2u(kb2.w, q2.w, a1);
                a1 = dot2u(kb3.x, q3.x, a1); a1 = dot2u(kb3.y, q3.y, a1);
                a1 = dot2u(kb3.z, q3.z, a1); a1 = dot2u(kb3.w, q3.w, a1);
                const uint4 s0 = qs4[h1*3 + 0], s1 = qs4[h1*3 + 1], s2 = qs4[h1*3 + 2];
                a1 = dot2u(pb0.x, s0.x, a1); a1 = dot2u(pb0.y, s0.y, a1);
                a1 = dot2u(pb0.z, s0.z, a1); a1 = dot2u(pb0.w, s0.w, a1);
                a1 = dot2u(pb1.x, s1.x, a1); a1 = dot2u(pb1.y, s1.y, a1);
                a1 = dot2u(pb1.z, s1.z, a1); a1 = dot2u(pb1.w, s1.w, a1);
                a1 = dot2u(pb2.x, s2.x, a1); a1 = dot2u(pb2.y, s2.y, a1);
                a1 = dot2u(pb2.z, s2.z, a1); a1 = dot2u(pb2.w, s2.w, a1);
                a1 = dot2u(rra.x, w1a.x, a1); a1 = dot2u(rra.y, w1a.y, a1);
                a1 = dot2u(rra.z, w1a.z, a1); a1 = dot2u(rra.w, w1a.w, a1);
                a1 = dot2u(rrb.x, w1b.x, a1); a1 = dot2u(rrb.y, w1b.y, a1);
                a1 = dot2u(rrb.z, w1b.z, a1); a1 = dot2u(rrb.w, w1b.w, a1);
            }
            lv[r][1] = pmv[r] ? (a1 + cia[r][h1] + vqa[h1]) * inv3 : -1e9f;
        }
    }

    // ================= Softmax: intra-wave + 8-wave combine per hp-group ====
    {
        float mx[4] = {lv[0][0], lv[0][1], lv[1][0], lv[1][1]};
#pragma unroll
        for (int off = 1; off < 64; off <<= 1) {
#pragma unroll
            for (int s = 0; s < 4; ++s) mx[s] = fmaxf(mx[s], __shfl_xor(mx[s], off));
        }
        if (lane == 0) *(float4*)&mxW[wv][0] = make_float4(mx[0], mx[1], mx[2], mx[3]);
        __syncthreads();
        float mxg[4] = {-1e30f, -1e30f, -1e30f, -1e30f};
        const int wbase = hp*8;
#pragma unroll
        for (int w = 0; w < 8; ++w) {
            const float4 m = *(const float4*)&mxW[wbase + w][0];
            mxg[0] = fmaxf(mxg[0], m.x); mxg[1] = fmaxf(mxg[1], m.y);
            mxg[2] = fmaxf(mxg[2], m.z); mxg[3] = fmaxf(mxg[3], m.w);
        }
        float e[4], sm[4];
        e[0] = pmv[0] ? __expf(lv[0][0] - mxg[0]) : 0.f;
        e[1] = pmv[0] ? __expf(lv[0][1] - mxg[1]) : 0.f;
        e[2] = pmv[1] ? __expf(lv[1][0] - mxg[2]) : 0.f;
        e[3] = pmv[1] ? __expf(lv[1][1] - mxg[3]) : 0.f;
#pragma unroll
        for (int s = 0; s < 4; ++s) sm[s] = e[s];
#pragma unroll
        for (int off = 1; off < 64; off <<= 1) {
#pragma unroll
            for (int s = 0; s < 4; ++s) sm[s] += __shfl_xor(sm[s], off);
        }
        if (lane == 0) *(float4*)&smW[wv][0] = make_float4(sm[0], sm[1], sm[2], sm[3]);
        __syncthreads();
        float smt[4] = {0.f, 0.f, 0.f, 0.f};
#pragma unroll
        for (int w = 0; w < 8; ++w) {
            const float4 m = *(const float4*)&smW[wbase + w][0];
            smt[0] += m.x; smt[1] += m.y; smt[2] += m.z; smt[3] += m.w;
        }
        float p[4];
#pragma unroll
        for (int s = 0; s < 4; ++s) {
            const float rden = 1.f / fmaxf(smt[s], 1e-37f);
            p[s] = e[s] * rden;
        }
        const int h0 = hp*2;
        atomicAdd(&abktW8[wv & 7][0][h0    ][rdv[0]], p[0]);
        atomicAdd(&abktW8[wv & 7][0][h0 + 1][rdv[0]], p[1]);
        atomicAdd(&abktW8[wv & 7][1][h0    ][rdv[1]], p[2]);
        atomicAdd(&abktW8[wv & 7][1][h0 + 1][rdv[1]], p[3]);
        if (j == 0) {
            asL2[0][h0]     = smt[0] / fmaxf(smt[0], 1e-37f);
            asL2[0][h0 + 1] = smt[1] / fmaxf(smt[1], 1e-37f);
            asL2[1][h0]     = smt[2] / fmaxf(smt[2], 1e-37f);
            asL2[1][h0 + 1] = smt[3] / fmaxf(smt[3], 1e-37f);
        }
#pragma unroll
        for (int s = 0; s < 4; ++s) {
            const float po = __shfl_xor(p[s], 1);
            if (!(j & 1)) {
                const int r = s >> 1, hh = s & 1;
                attnH2[r*4 + h0 + hh][j >> 1] = packh2(p[s], po);
            }
        }
    }
    __syncthreads();

    // ================= Pass B: MFMA P(8 rows) x [val|kp], + rbf waves =======
    if (wv < 14) {
        const int row = lane & 15;
        const int ntA = wv;
        const int ntB = (wv < 6) ? (wv + 14) : -1;
        f32x4 accA = {0.f,0.f,0.f,0.f};
        f32x4 accB = {0.f,0.f,0.f,0.f};
        const uint4* bfp = (const uint4*)BF;
#pragma unroll 4
        for (int kt = 0; kt < 16; ++kt) {
            uint4 au = make_uint4(0u, 0u, 0u, 0u);
            if (row < 8) au = *(const uint4*)&attnH2[row][kt*16 + (lane >> 4)*4];
            const uint4 bA = bfp[(ntA*16 + kt)*64 + lane];
            accA = mfma16(au, bA, accA);
            if (ntB >= 0) {
                const uint4 bB = bfp[(ntB*16 + kt)*64 + lane];
                accB = mfma16(au, bB, accB);
            }
        }
        if (lane < 32) {
            const int r = lane >> 4, c16 = lane & 15;
            {
                const int s = ntA*16 + c16;
                if (s < HPC) {
                    resL2[r][s] = ((const float*)&accA)[s / PAIR_CN];
                } else {
                    const int f = s - HPC;
                    GLfF2[r][0][f] = accA[0];
                    GLfF2[r][1][f] = accA[1];
                    GLfF2[r][2][f] = accA[2];
                    GLfF2[r][3][f] = accA[3];
                }
            }
            if (ntB >= 0) {
                const int s = ntB*16 + c16;
                if (s < HPC) {
                    resL2[r][s] = ((const float*)&accB)[s / PAIR_CN];
                } else {
                    const int f = s - HPC;
                    GLfF2[r][0][f] = accB[0];
                    GLfF2[r][1][f] = accB[1];
                    GLfF2[r][2][f] = accB[2];
                    GLfF2[r][3][f] = accB[3];
                }
            }
        }
    } else {
        // rbf-G: wave 14 -> row 0, wave 15 -> row 1
        const int r = wv - 14;
        const int b = lane >> 2, q = lane & 3;
        const int w = b >> 1;
        const bool hi = (b & 1);
        float a[4] = {0.f, 0.f, 0.f, 0.f};
#pragma unroll 4
        for (int jpp = q*64; jpp < q*64 + 64; ++jpp) {
            const unsigned r0 = rbfP[r][2*jpp][w];
            const unsigned r1 = rbfP[r][2*jpp + 1][w];
            const unsigned ee = hi ? ((r0 >> 16) | (r1 & 0xffff0000u))
                                   : ((r0 & 0xffffu) | (r1 << 16));
            a[0] = dot2u(ee, attnH2[r*4 + 0][jpp], a[0]);
            a[1] = dot2u(ee, attnH2[r*4 + 1][jpp], a[1]);
            a[2] = dot2u(ee, attnH2[r*4 + 2][jpp], a[2]);
            a[3] = dot2u(ee, attnH2[r*4 + 3][jpp], a[3]);
        }
#pragma unroll
        for (int h = 0; h < 4; ++h) {
            a[h] += __shfl_xor(a[h], 1);
            a[h] += __shfl_xor(a[h], 2);
            if (q == 0) GLfR2[r][h][b] = a[h];
        }
    }
    __syncthreads();

    // ================= Combine: GLf2 pack, bucket pack ====================
    for (int t = tid; t < 448; t += 1024) {   // t = r*224 + h*56 + f2
        const int r = t / 224, v = t % 224, h = v / 56, f2 = v % 56;
        if (f2 < 48) {
            GLf22[r][h][f2] = packh2(qpiL2[r][2*f2]*asL2[r][h]     - GLfF2[r][h][2*f2],
                                     qpiL2[r][2*f2 + 1]*asL2[r][h] - GLfF2[r][h][2*f2 + 1]);
        } else {
            GLf22[r][h][f2] = packh2(GLfR2[r][h][(f2 - 48)*2], GLfR2[r][h][(f2 - 48)*2 + 1]);
        }
    }
    for (int t = tid; t < 264; t += 1024) {   // t = r*132 + h*33 + r2
        const int r = t / 132, v = t % 132, h = v / 33, r2 = v % 33;
        float s0 = 0.f, s1 = 0.f;
#pragma unroll
        for (int w = 0; w < 8; ++w) {
            s0 += abktW8[w][r][h][2*r2];
            s1 += abktW8[w][r][h][2*r2 + 1];
        }
        abktP2[r][h][r2] = packh2(s0, s1);
    }
    __syncthreads();

    // ================= Epilogue: weights loaded once, 2 rows ================
    if (tid < HPC) {
        const int h = tid / PAIR_CN, c = tid - h*PAIR_CN;
        float r0 = resL2[0][tid];
        float r1 = resL2[1][tid];
        {
            unsigned buf[16];
#pragma unroll
            for (int t = 0; t < 16; ++t) buf[t] = remb2[t*56 + c];
#pragma unroll
            for (int t = 0; t < 16; ++t) {
                r0 = dot2u(buf[t], abktP2[0][h][t], r0);
                r1 = dot2u(buf[t], abktP2[1][h][t], r1);
            }
#pragma unroll
            for (int t = 0; t < 16; ++t) buf[t] = remb2[(16 + t)*56 + c];
#pragma unroll
            for (int t = 0; t < 16; ++t) {
                r0 = dot2u(buf[t], abktP2[0][h][16 + t], r0);
                r1 = dot2u(buf[t], abktP2[1][h][16 + t], r1);
            }
            const unsigned b32 = remb2[32*56 + c];
            r0 = dot2u(b32, abktP2[0][h][32], r0);
            r1 = dot2u(b32, abktP2[1][h][32], r1);
        }
        {
            unsigned buf[14];
#pragma unroll
            for (int qq = 0; qq < 4; ++qq) {
#pragma unroll
                for (int t = 0; t < 14; ++t) buf[t] = wp2[(qq*14 + t)*56 + c];
#pragma unroll
                for (int t = 0; t < 14; ++t) {
                    r0 = dot2u(buf[t], GLf22[0][h][qq*14 + t], r0);
                    r1 = dot2u(buf[t], GLf22[1][h][qq*14 + t], r1);
                }
            }
        }
        resL2[0][tid] = r0;
        resL2[1][tid] = r1;
    }
    __syncthreads();

    if (tid < 2*FD_N) {
        const int r = tid / FD_N, t2 = tid % FD_N;
        resH2[r][t2] = packh2(resL2[r][2*t2], resL2[r][2*t2 + 1]);
    }
    __syncthreads();

    // ================= out: woPk loaded once, 2 rows =======================
    if (tid < 512) {
        const int col = tid >> 1, ph = tid & 1;
        float o0 = 0.f, o1 = 0.f;
        unsigned buf[14];
#pragma unroll
        for (int qq = 0; qq < 4; ++qq) {
            const int base = ph*56 + qq*14;
#pragma unroll
            for (int t = 0; t < 14; ++t) buf[t] = woPk[(base + t)*256 + col];
#pragma unroll
            for (int t = 0; t < 14; ++t) {
                o0 = dot2u(buf[t], resH2[0][base + t], o0);
                o1 = dot2u(buf[t], resH2[1][base + t], o1);
            }
        }
        o0 += __shfl_xor(o0, 1);
        o1 += __shfl_xor(o1, 1);
        if (ph == 0) {
            out[(size_t)ib*DIM + col]       = o0;
            out[(size_t)(ib + 1)*DIM + col] = o1;
        }
    }
}

// ---------------------------------------------------------------------------
extern "C" void kernel_launch(void* const* d_in, const int* in_sizes, int n_in,
                              void* d_out, int out_size, void* d_ws, size_t ws_size,
                              hipStream_t stream) {
    (void)in_sizes; (void)n_in; (void)out_size; (void)ws_size;
    const float* local = (const float*)d_in[0];
    const float* pos   = (const float*)d_in[1];
    const int*   resi  = (const int*)d_in[2];
    const int*   chain = (const int*)d_in[3];
    const int*   batch = (const int*)d_in[4];
    const void*  maskp = d_in[5];
    const float* qls   = (const float*)d_in[6];
    const float* qlo   = (const float*)d_in[7];
    const float* kls   = (const float*)d_in[8];
    const float* klo   = (const float*)d_in[9];
    const float* w_q   = (const float*)d_in[10];
    const float* b_q   = (const float*)d_in[11];
    const float* w_k   = (const float*)d_in[12];
    const float* b_k   = (const float*)d_in[13];
    const float* w_v   = (const float*)d_in[14];
    const float* b_v   = (const float*)d_in[15];
    const float* w_qp  = (const float*)d_in[16];
    const float* b_qp  = (const float*)d_in[17];
    const float* w_kp  = (const float*)d_in[18];
    const float* b_kp  = (const float*)d_in[19];
    const float* w_vp  = (const float*)d_in[20];
    const float* b_vp  = (const float*)d_in[21];
    const float* remb  = (const float*)d_in[22];
    const float* w_pair= (const float*)d_in[23];
    const float* w_bias= (const float*)d_in[24];
    const float* b_bias= (const float*)d_in[25];
    const float* gamma = (const float*)d_in[26];
    const float* w_out = (const float*)d_in[27];

    char* ws = (char*)d_ws;
    unsigned* qnP   = (unsigned*)(ws);            // 131072 B [512][64]
    unsigned* qpP   = (unsigned*)(ws + 131072);   //  98304 B [512][48]
    unsigned* knT4  = (unsigned*)(ws + 229376);   // 131072 B [16][512][4]
    unsigned* kpT4  = (unsigned*)(ws + 360448);   //  98304 B [12][512][4]
    unsigned* BF    = (unsigned*)(ws + 458752);   // 327680 B [20][16][64][4]
    float*    jinf  = (float*)(ws + 786432);      //  16384 B
    float*    iinf  = (float*)(ws + 802816);      //   8192 B
    unsigned* woPk  = (unsigned*)(ws + 811008);   // 114688 B [112][256]
    unsigned* wp2   = (unsigned*)(ws + 925696);   //  12544 B [56][56]
    unsigned* remb2 = (unsigned*)(ws + 938240);   //   7392 B [33][56]

    proj_kernel<<<N_NODES / 2, 512, 0, stream>>>(
        local, pos, qls, qlo, kls, klo,
        w_q, b_q, w_k, b_k, w_v, b_v,
        w_qp, b_qp, w_kp, b_kp, w_vp, b_vp,
        w_bias, b_bias, gamma,
        remb, w_pair, w_out,
        qnP, knT4, qpP, kpT4, BF,
        woPk, wp2, remb2, jinf, iinf);

    attn_kernel<<<N_NODES / 2, 1024, 0, stream>>>(
        qnP, knT4, qpP, kpT4, BF,
        woPk, wp2, remb2, jinf, iinf,
        resi, chain, batch, maskp,
        w_bias, gamma,
        (float*)d_out);
}